// Round 2
// baseline (1999.213 us; speedup 1.0000x reference)
//
#include <hip/hip_runtime.h>
#include <hip/hip_bf16.h>
#include <cstdint>

#define BB 2
#define SS 4096
#define DD 768
#define HH 12
#define GG 64
#define WW 256

typedef __hip_bfloat16 bf16;
typedef unsigned short u16;

__device__ __forceinline__ float b2f(u16 u) {
  return __uint_as_float(((unsigned int)u) << 16);
}
__device__ __forceinline__ float wave_max(float v) {
#pragma unroll
  for (int o = 32; o > 0; o >>= 1) v = fmaxf(v, __shfl_xor(v, o));
  return v;
}
__device__ __forceinline__ float wave_sum(float v) {
#pragma unroll
  for (int o = 32; o > 0; o >>= 1) v += __shfl_xor(v, o);
  return v;
}
__device__ __forceinline__ float lane_bcast(float v, int l) {
  return __uint_as_float((unsigned)__builtin_amdgcn_readlane((int)__float_as_uint(v), l));
}

// Detect whether float tensors are fp32 (flag=1) or bf16 (flag=0) by
// interpreting query's first 4096 ushorts as bf16: an fp32 buffer's
// low-mantissa halves give ~47% wild/NaN values; a true bf16 N(0,1)
// buffer gives none.
__global__ __launch_bounds__(256) void detect_dtype(const u16* __restrict__ q,
                                                    int* __restrict__ flag) {
  __shared__ int cnt;
  int tid = threadIdx.x;
  if (tid == 0) cnt = 0;
  __syncthreads();
  int bad = 0;
#pragma unroll
  for (int i = 0; i < 16; ++i) {
    float f = b2f(q[tid * 16 + i]);
    if (!isfinite(f) || fabsf(f) > 100.f) bad++;
  }
  atomicAdd(&cnt, bad);
  __syncthreads();
  if (tid == 0) *flag = (cnt > 256) ? 1 : 0;
}

// Canonicalize a float tensor (fp32 or bf16 per *flag) into bf16.
__global__ __launch_bounds__(256) void canon_bf16(const void* __restrict__ src,
                                                  bf16* __restrict__ dst, int n,
                                                  const int* __restrict__ flag) {
  bool f32 = (*flag != 0);
  for (int i = blockIdx.x * 256 + threadIdx.x; i < n; i += gridDim.x * 256) {
    float v = f32 ? ((const float*)src)[i] : b2f(((const u16*)src)[i]);
    dst[i] = __float2bfloat16(v);
  }
}

// C[r,n] = (sum_k X[r,k]*W[k,n] + bias[n]) * scale ; K=N=768, X/W/bias bf16.
// MODE 0: bf16 heads layout out[((b*H+h)*Sdim + s)*64 + hd], r=(s*B+b), n=h*64+hd
// MODE 1: fp32 flat out[r*768+n]
template <int MODE>
__global__ __launch_bounds__(256) void gemm_bias(
    const bf16* __restrict__ Xb, const bf16* __restrict__ Wb,
    const bf16* __restrict__ biasb, void* __restrict__ outv, int Sdim,
    float scale) {
  __shared__ __align__(16) float Xs[16][64];
  __shared__ __align__(16) float Ws[16][68];
  const u16* X = (const u16*)Xb;
  const u16* Wm = (const u16*)Wb;
  const u16* bias = (const u16*)biasb;
  int tid = threadIdx.x;
  int bm = blockIdx.x * 64, bn = blockIdx.y * 64;
  int tx = tid & 15, ty = tid >> 4;
  int lrowX = tid >> 2, lkX = (tid & 3) << 2;
  int lkW = tid >> 4, lnW = (tid & 15) << 2;
  float acc[4][4] = {};
  for (int k0 = 0; k0 < DD; k0 += 16) {
    ushort4 ux = *(const ushort4*)(X + (size_t)(bm + lrowX) * DD + k0 + lkX);
    ushort4 uw = *(const ushort4*)(Wm + (size_t)(k0 + lkW) * DD + bn + lnW);
    __syncthreads();
    Xs[lkX + 0][lrowX] = b2f(ux.x);
    Xs[lkX + 1][lrowX] = b2f(ux.y);
    Xs[lkX + 2][lrowX] = b2f(ux.z);
    Xs[lkX + 3][lrowX] = b2f(ux.w);
    Ws[lkW][lnW + 0] = b2f(uw.x);
    Ws[lkW][lnW + 1] = b2f(uw.y);
    Ws[lkW][lnW + 2] = b2f(uw.z);
    Ws[lkW][lnW + 3] = b2f(uw.w);
    __syncthreads();
#pragma unroll
    for (int kk = 0; kk < 16; ++kk) {
      float4 a = *(const float4*)&Xs[kk][ty << 2];
      float4 w4 = *(const float4*)&Ws[kk][tx << 2];
      float av[4] = {a.x, a.y, a.z, a.w};
      float wv[4] = {w4.x, w4.y, w4.z, w4.w};
#pragma unroll
      for (int i = 0; i < 4; ++i)
#pragma unroll
        for (int j = 0; j < 4; ++j) acc[i][j] = fmaf(av[i], wv[j], acc[i][j]);
    }
  }
  float bia[4];
#pragma unroll
  for (int j = 0; j < 4; ++j) bia[j] = b2f(bias[bn + (tx << 2) + j]);
#pragma unroll
  for (int i = 0; i < 4; ++i) {
    int r = bm + (ty << 2) + i;
    int s = r >> 1, b = r & 1;
#pragma unroll
    for (int j = 0; j < 4; ++j) {
      int n = bn + (tx << 2) + j;
      float val = (acc[i][j] + bia[j]) * scale;
      if (MODE == 0) {
        int h = n >> 6, hd = n & 63;
        ((bf16*)outv)[(((size_t)(b * HH + h)) * Sdim + s) * 64 + hd] =
            __float2bfloat16(val);
      } else {
        ((float*)outv)[(size_t)r * DD + n] = val;
      }
    }
  }
}

// Local+global-key attention for rows s >= G. Block: (bh, 64-row tile).
__global__ __launch_bounds__(256) void attn_local(
    const bf16* __restrict__ qb, const bf16* __restrict__ kb_,
    const bf16* __restrict__ vb, const int* __restrict__ kpm,
    bf16* __restrict__ attnout) {
  __shared__ __align__(16) float qs[64][64];
  __shared__ __align__(16) float ks[64][68];
  __shared__ __align__(16) float vs[64][68];
  int bid = blockIdx.x;
  int sblk = bid & 63;
  if (sblk == 0) return;  // rows < G handled by global path
  int bh = bid >> 6;
  int b = bh / HH, h = bh % HH;
  int tid = threadIdx.x, lane = tid & 63, w = tid >> 6;
  size_t base = (size_t)bh * SS * 64;
  int sq0 = sblk * 64;
  const u16* qp = (const u16*)qb + base;
  const u16* kp = (const u16*)kb_ + base;
  const u16* vp = (const u16*)vb + base;
#pragma unroll
  for (int i = 0; i < 4; ++i) {
    int e = (tid + i * 256) << 2;
    int row = e >> 6, d = e & 63;
    ushort4 u = *(const ushort4*)(qp + (size_t)(sq0 + row) * 64 + d);
    qs[row][d + 0] = b2f(u.x);
    qs[row][d + 1] = b2f(u.y);
    qs[row][d + 2] = b2f(u.z);
    qs[row][d + 3] = b2f(u.w);
  }
  float O[16], pm[16], pl[16], alp[16], pr[16];
#pragma unroll
  for (int rr = 0; rr < 16; ++rr) {
    O[rr] = 0.f;
    pm[rr] = -3.0e38f;
    pl[rr] = 0.f;
  }
  int win_lo = max(sq0 - WW, GG);
  int win_hi = min(sq0 + 63 + WW, SS - 1);
  int kb_lo = win_lo & ~63;
  int nkb = ((win_hi - kb_lo) >> 6) + 1;
  int wr0 = w * 16;
  for (int it = 0; it <= nkb; ++it) {
    int kbs = (it == 0) ? 0 : kb_lo + ((it - 1) << 6);
    __syncthreads();
#pragma unroll
    for (int i = 0; i < 4; ++i) {
      int e = (tid + i * 256) << 2;
      int row = e >> 6, d = e & 63;
      ushort4 uk = *(const ushort4*)(kp + (size_t)(kbs + row) * 64 + d);
      ushort4 uv = *(const ushort4*)(vp + (size_t)(kbs + row) * 64 + d);
      ks[row][d + 0] = b2f(uk.x);
      ks[row][d + 1] = b2f(uk.y);
      ks[row][d + 2] = b2f(uk.z);
      ks[row][d + 3] = b2f(uk.w);
      vs[row][d + 0] = b2f(uv.x);
      vs[row][d + 1] = b2f(uv.y);
      vs[row][d + 2] = b2f(uv.z);
      vs[row][d + 3] = b2f(uv.w);
    }
    __syncthreads();
    int kpos = kbs + lane;
    int kbad = kpm[b * SS + kpos];
#pragma unroll
    for (int g = 0; g < 4; ++g) {
      float d0 = 0.f, d1 = 0.f, d2 = 0.f, d3 = 0.f;
#pragma unroll
      for (int c = 0; c < 16; ++c) {
        float4 kx = *(const float4*)&ks[lane][c << 2];
        float4 q0 = *(const float4*)&qs[wr0 + (g << 2) + 0][c << 2];
        float4 q1 = *(const float4*)&qs[wr0 + (g << 2) + 1][c << 2];
        float4 q2 = *(const float4*)&qs[wr0 + (g << 2) + 2][c << 2];
        float4 q3 = *(const float4*)&qs[wr0 + (g << 2) + 3][c << 2];
        d0 = fmaf(kx.x, q0.x, fmaf(kx.y, q0.y, fmaf(kx.z, q0.z, fmaf(kx.w, q0.w, d0))));
        d1 = fmaf(kx.x, q1.x, fmaf(kx.y, q1.y, fmaf(kx.z, q1.z, fmaf(kx.w, q1.w, d1))));
        d2 = fmaf(kx.x, q2.x, fmaf(kx.y, q2.y, fmaf(kx.z, q2.z, fmaf(kx.w, q2.w, d2))));
        d3 = fmaf(kx.x, q3.x, fmaf(kx.y, q3.y, fmaf(kx.z, q3.z, fmaf(kx.w, q3.w, d3))));
      }
      float dots[4] = {d0, d1, d2, d3};
#pragma unroll
      for (int r = 0; r < 4; ++r) {
        int rr = (g << 2) + r;
        int qr = sq0 + wr0 + rr;
        bool valid;
        if (it == 0)
          valid = true;  // global keys: unmasked in reference gsc
        else
          valid = (kpos >= qr - WW) && (kpos <= qr + WW) && (kpos >= GG) &&
                  (kbad == 0);
        float sc = valid ? dots[r] : -3.0e38f;
        float bmax = wave_max(sc);
        float mnew = fmaxf(pm[rr], bmax);
        float a = __expf(pm[rr] - mnew);
        float p = valid ? __expf(dots[r] - mnew) : 0.f;
        float psum = wave_sum(p);
        pl[rr] = pl[rr] * a + psum;
        pm[rr] = mnew;
        alp[rr] = a;
        pr[rr] = p;
      }
    }
#pragma unroll
    for (int rr = 0; rr < 16; ++rr) O[rr] *= alp[rr];
    for (int l4 = 0; l4 < 64; ++l4) {
      float vv = vs[l4][lane];
#pragma unroll
      for (int rr = 0; rr < 16; ++rr) {
        float pb = lane_bcast(pr[rr], l4);
        O[rr] = fmaf(pb, vv, O[rr]);
      }
    }
  }
#pragma unroll
  for (int rr = 0; rr < 16; ++rr) {
    int qr = sq0 + wr0 + rr;
    float o = O[rr] / pl[rr];
    attnout[((size_t)qr * BB + b) * DD + h * 64 + lane] = __float2bfloat16(o);
  }
}

// Global-row attention (rows s<G) over one key segment of 256 keys; writes
// flash partials (O, m, l).
__global__ __launch_bounds__(256) void attn_glb(
    const bf16* __restrict__ qgb, const bf16* __restrict__ kgb,
    const bf16* __restrict__ vgb, const int* __restrict__ kpm,
    float* __restrict__ part) {
  __shared__ __align__(16) float qs[64][64];
  __shared__ __align__(16) float ks[64][68];
  __shared__ __align__(16) float vs[64][68];
  int bid = blockIdx.x;  // bh*16 + seg
  int bh = bid >> 4, seg = bid & 15;
  int b = bh / HH;
  int tid = threadIdx.x, lane = tid & 63, w = tid >> 6;
  const u16* qp = (const u16*)qgb + (size_t)bh * GG * 64;
  size_t base = (size_t)bh * SS * 64;
  const u16* kp = (const u16*)kgb + base;
  const u16* vp = (const u16*)vgb + base;
#pragma unroll
  for (int i = 0; i < 4; ++i) {
    int e = (tid + i * 256) << 2;
    int row = e >> 6, d = e & 63;
    ushort4 u = *(const ushort4*)(qp + (size_t)row * 64 + d);
    qs[row][d + 0] = b2f(u.x);
    qs[row][d + 1] = b2f(u.y);
    qs[row][d + 2] = b2f(u.z);
    qs[row][d + 3] = b2f(u.w);
  }
  float O[16], pm[16], pl[16], alp[16], pr[16];
#pragma unroll
  for (int rr = 0; rr < 16; ++rr) {
    O[rr] = 0.f;
    pm[rr] = -3.0e38f;
    pl[rr] = 0.f;
  }
  int wr0 = w * 16;
  for (int it = 0; it < 4; ++it) {
    int kbs = (seg << 8) + (it << 6);
    __syncthreads();
#pragma unroll
    for (int i = 0; i < 4; ++i) {
      int e = (tid + i * 256) << 2;
      int row = e >> 6, d = e & 63;
      ushort4 uk = *(const ushort4*)(kp + (size_t)(kbs + row) * 64 + d);
      ushort4 uv = *(const ushort4*)(vp + (size_t)(kbs + row) * 64 + d);
      ks[row][d + 0] = b2f(uk.x);
      ks[row][d + 1] = b2f(uk.y);
      ks[row][d + 2] = b2f(uk.z);
      ks[row][d + 3] = b2f(uk.w);
      vs[row][d + 0] = b2f(uv.x);
      vs[row][d + 1] = b2f(uv.y);
      vs[row][d + 2] = b2f(uv.z);
      vs[row][d + 3] = b2f(uv.w);
    }
    __syncthreads();
    int kpos = kbs + lane;
    bool valid = (kpm[b * SS + kpos] <= 0);  // only is_pad masks (kpm>0)
#pragma unroll
    for (int g = 0; g < 4; ++g) {
      float d0 = 0.f, d1 = 0.f, d2 = 0.f, d3 = 0.f;
#pragma unroll
      for (int c = 0; c < 16; ++c) {
        float4 kx = *(const float4*)&ks[lane][c << 2];
        float4 q0 = *(const float4*)&qs[wr0 + (g << 2) + 0][c << 2];
        float4 q1 = *(const float4*)&qs[wr0 + (g << 2) + 1][c << 2];
        float4 q2 = *(const float4*)&qs[wr0 + (g << 2) + 2][c << 2];
        float4 q3 = *(const float4*)&qs[wr0 + (g << 2) + 3][c << 2];
        d0 = fmaf(kx.x, q0.x, fmaf(kx.y, q0.y, fmaf(kx.z, q0.z, fmaf(kx.w, q0.w, d0))));
        d1 = fmaf(kx.x, q1.x, fmaf(kx.y, q1.y, fmaf(kx.z, q1.z, fmaf(kx.w, q1.w, d1))));
        d2 = fmaf(kx.x, q2.x, fmaf(kx.y, q2.y, fmaf(kx.z, q2.z, fmaf(kx.w, q2.w, d2))));
        d3 = fmaf(kx.x, q3.x, fmaf(kx.y, q3.y, fmaf(kx.z, q3.z, fmaf(kx.w, q3.w, d3))));
      }
      float dots[4] = {d0, d1, d2, d3};
#pragma unroll
      for (int r = 0; r < 4; ++r) {
        int rr = (g << 2) + r;
        float sc = valid ? dots[r] : -3.0e38f;
        float bmax = wave_max(sc);
        float mnew = fmaxf(pm[rr], bmax);
        float a = __expf(pm[rr] - mnew);
        float p = valid ? __expf(dots[r] - mnew) : 0.f;
        float psum = wave_sum(p);
        pl[rr] = pl[rr] * a + psum;
        pm[rr] = mnew;
        alp[rr] = a;
        pr[rr] = p;
      }
    }
#pragma unroll
    for (int rr = 0; rr < 16; ++rr) O[rr] *= alp[rr];
    for (int l4 = 0; l4 < 64; ++l4) {
      float vv = vs[l4][lane];
#pragma unroll
      for (int rr = 0; rr < 16; ++rr) {
        float pb = lane_bcast(pr[rr], l4);
        O[rr] = fmaf(pb, vv, O[rr]);
      }
    }
  }
  float* pO = part + (size_t)bid * 4224;
#pragma unroll
  for (int rr = 0; rr < 16; ++rr) {
    int row = wr0 + rr;
    pO[(row << 6) + lane] = O[rr];
    if (lane == 0) {
      pO[4096 + row] = pm[rr];
      pO[4160 + row] = pl[rr];
    }
  }
}

__global__ __launch_bounds__(256) void attn_comb(const float* __restrict__ part,
                                                 bf16* __restrict__ attnout) {
  int tid = threadIdx.x, lane = tid & 63, w = tid >> 6;
  int idx = blockIdx.x * 4 + w;  // [0, B*H*G)
  int bh = idx >> 6, row = idx & 63;
  int b = bh / HH, h = bh % HH;
  float M = -3.0e38f;
#pragma unroll
  for (int s16 = 0; s16 < 16; ++s16) {
    float ms = part[((size_t)(bh * 16 + s16)) * 4224 + 4096 + row];
    M = fmaxf(M, ms);
  }
  float L = 0.f, o = 0.f;
#pragma unroll
  for (int s16 = 0; s16 < 16; ++s16) {
    const float* p = part + ((size_t)(bh * 16 + s16)) * 4224;
    float sc = __expf(p[4096 + row] - M);
    o += sc * p[(row << 6) + lane];
    L += sc * p[4160 + row];
  }
  attnout[((size_t)row * BB + b) * DD + h * 64 + lane] = __float2bfloat16(o / L);
}

extern "C" void kernel_launch(void* const* d_in, const int* in_sizes, int n_in,
                              void* d_out, int out_size, void* d_ws,
                              size_t ws_size, hipStream_t stream) {
  const int* kpm = (const int*)d_in[1];
  float* outp = (float*)d_out;
  const size_t SZ = (size_t)BB * HH * SS * 64;  // 6,291,456
  const size_t WSZ = (size_t)DD * DD;           // 589,824
  bf16* p = (bf16*)d_ws;
  bf16* cQ = p; p += SZ;              // canonical query (S,B,D) bf16
  bf16* cW[7];
  bf16* cB[7];
  for (int i = 0; i < 7; ++i) { cW[i] = p; p += WSZ; }
  for (int i = 0; i < 7; ++i) { cB[i] = p; p += DD; }
  bf16* q = p; p += SZ;
  bf16* k = p; p += SZ;
  bf16* v = p; p += SZ;
  bf16* kg = p; p += SZ;
  bf16* vg = p; p += SZ;
  bf16* qg = p; p += (size_t)BB * HH * GG * 64;  // 98,304
  bf16* attnout = p; p += SZ;
  float* part = (float*)p;            // 384*4224 floats
  int* flag = (int*)(part + (size_t)384 * 4224);
  const float SC = 0.125f;
  dim3 blk(256);

  detect_dtype<<<1, blk, 0, stream>>>((const u16*)d_in[0], flag);
  // canonicalize: query + 7 (W,b) pairs, input dict order W at 2,4,6,8,10,12,14
  canon_bf16<<<dim3(2048), blk, 0, stream>>>(d_in[0], cQ, (int)SZ, flag);
  for (int i = 0; i < 7; ++i) {
    canon_bf16<<<dim3(1152), blk, 0, stream>>>(d_in[2 + 2 * i], cW[i], (int)WSZ, flag);
    canon_bf16<<<dim3(3), blk, 0, stream>>>(d_in[3 + 2 * i], cB[i], DD, flag);
  }
  // cW/cB order: q, k, v, qg, kg, vg, o
  gemm_bias<0><<<dim3(128, 12), blk, 0, stream>>>(cQ, cW[0], cB[0], q, SS, SC);
  gemm_bias<0><<<dim3(128, 12), blk, 0, stream>>>(cQ, cW[1], cB[1], k, SS, 1.f);
  gemm_bias<0><<<dim3(128, 12), blk, 0, stream>>>(cQ, cW[2], cB[2], v, SS, 1.f);
  gemm_bias<0><<<dim3(128, 12), blk, 0, stream>>>(cQ, cW[4], cB[4], kg, SS, 1.f);
  gemm_bias<0><<<dim3(128, 12), blk, 0, stream>>>(cQ, cW[5], cB[5], vg, SS, 1.f);
  gemm_bias<0><<<dim3(2, 12), blk, 0, stream>>>(cQ, cW[3], cB[3], qg, GG, SC);
  attn_local<<<dim3(BB * HH * 64), blk, 0, stream>>>(q, k, v, kpm, attnout);
  attn_glb<<<dim3(BB * HH * 16), blk, 0, stream>>>(qg, kg, vg, kpm, part);
  attn_comb<<<dim3(BB * HH * 16), blk, 0, stream>>>(part, attnout);
  gemm_bias<1><<<dim3(128, 12), blk, 0, stream>>>(attnout, cW[6], cB[6], outp, 0, 1.f);
}

// Round 3
// 397.002 us; speedup vs baseline: 5.0358x; 5.0358x over previous
//
#include <hip/hip_runtime.h>
#include <hip/hip_bf16.h>
#include <cstdint>

#define BB 2
#define SS 4096
#define DD 768
#define HH 12
#define GG 64
#define WW 256

typedef __hip_bfloat16 bf16;
typedef unsigned short u16;
typedef __attribute__((ext_vector_type(8))) short short8v;
typedef __attribute__((ext_vector_type(4))) float floatx4;

__device__ __forceinline__ float b2f(u16 u) {
  return __uint_as_float(((unsigned int)u) << 16);
}
__device__ __forceinline__ u16 f2bu(float f) {
  bf16 h = __float2bfloat16(f);
  return *reinterpret_cast<u16*>(&h);
}

// ---- dtype detect + canonicalize (inputs may be fp32 or bf16) ----
__global__ __launch_bounds__(256) void detect_dtype(const u16* __restrict__ q,
                                                    int* __restrict__ flag) {
  __shared__ int cnt;
  int tid = threadIdx.x;
  if (tid == 0) cnt = 0;
  __syncthreads();
  int bad = 0;
#pragma unroll
  for (int i = 0; i < 16; ++i) {
    float f = b2f(q[tid * 16 + i]);
    if (!isfinite(f) || fabsf(f) > 100.f) bad++;
  }
  atomicAdd(&cnt, bad);
  __syncthreads();
  if (tid == 0) *flag = (cnt > 256) ? 1 : 0;
}

__global__ __launch_bounds__(256) void canon_bf16(const void* __restrict__ src,
                                                  bf16* __restrict__ dst, int n,
                                                  const int* __restrict__ flag) {
  bool f32 = (*flag != 0);
  for (int i = blockIdx.x * 256 + threadIdx.x; i < n; i += gridDim.x * 256) {
    float v = f32 ? ((const float*)src)[i] : b2f(((const u16*)src)[i]);
    dst[i] = __float2bfloat16(v);
  }
}

// W[K][N] (768x768) -> Wt[N][K] bf16, 32x32 LDS tiles.
__global__ __launch_bounds__(256) void transpose_w(const void* __restrict__ src,
                                                   bf16* __restrict__ dst,
                                                   const int* __restrict__ flag) {
  __shared__ float tile[32][33];
  bool f32 = (*flag != 0);
  int tx = threadIdx.x & 31, ty = threadIdx.x >> 5;
  int k0 = blockIdx.x * 32, n0 = blockIdx.y * 32;
#pragma unroll
  for (int i = 0; i < 32; i += 8) {
    int k = k0 + ty + i, n = n0 + tx;
    float v = f32 ? ((const float*)src)[(size_t)k * DD + n]
                  : b2f(((const u16*)src)[(size_t)k * DD + n]);
    tile[ty + i][tx] = v;
  }
  __syncthreads();
#pragma unroll
  for (int i = 0; i < 32; i += 8) {
    int n = n0 + ty + i, k = k0 + tx;
    dst[(size_t)n * DD + k] = __float2bfloat16(tile[tx][ty + i]);
  }
}

// ---- MFMA GEMM: C[m,n] = (sum_k X[m,k]*W[k,n] + bias[n]) * scale ----
// X: [M][768] bf16 row-major. Wt: [N][K] bf16 (pre-transposed W). K=N=768.
// MODE 0: bf16 heads layout out[((b*H+h)*Sdim+s)*64+hd], m=(s*B+b), n=h*64+hd
// MODE 1: fp32 flat out[m*768+n]
template <int MODE>
__global__ __launch_bounds__(256) void gemm_mfma(
    const bf16* __restrict__ Xb, const bf16* __restrict__ Wtb,
    const bf16* __restrict__ biasb, void* __restrict__ outv, int Sdim,
    float scale) {
  __shared__ __align__(16) u16 As[128][40];  // [m][k], stride 80B
  __shared__ __align__(16) u16 Bs[128][40];  // [n][k]
  const u16* Xp = (const u16*)Xb;
  const u16* Wp = (const u16*)Wtb;
  const u16* bias = (const u16*)biasb;
  int tid = threadIdx.x;
  int bm = blockIdx.x * 128, bn = blockIdx.y * 128;
  int lane = tid & 63, w = tid >> 6, quad = lane >> 4, t = lane & 15;
  int wm = (w >> 1) * 64, wn = (w & 1) * 64;
  int sr = tid >> 1, skp = (tid & 1) * 16;
  floatx4 acc[4][4];
#pragma unroll
  for (int i = 0; i < 4; ++i)
#pragma unroll
    for (int j = 0; j < 4; ++j) acc[i][j] = (floatx4)(0.f);
  for (int k0 = 0; k0 < DD; k0 += 32) {
    ushort4 ax[4], bx[4];
#pragma unroll
    for (int i = 0; i < 4; ++i) {
      ax[i] = *(const ushort4*)(Xp + (size_t)(bm + sr) * DD + k0 + skp + 4 * i);
      bx[i] = *(const ushort4*)(Wp + (size_t)(bn + sr) * DD + k0 + skp + 4 * i);
    }
    __syncthreads();
#pragma unroll
    for (int i = 0; i < 4; ++i) {
      *(ushort4*)&As[sr][skp + 4 * i] = ax[i];
      *(ushort4*)&Bs[sr][skp + 4 * i] = bx[i];
    }
    __syncthreads();
    short8v a[4], bfr[4];
#pragma unroll
    for (int mt = 0; mt < 4; ++mt)
      a[mt] = *(const short8v*)&As[wm + mt * 16 + t][quad * 8];
#pragma unroll
    for (int nt = 0; nt < 4; ++nt)
      bfr[nt] = *(const short8v*)&Bs[wn + nt * 16 + t][quad * 8];
#pragma unroll
    for (int mt = 0; mt < 4; ++mt)
#pragma unroll
      for (int nt = 0; nt < 4; ++nt)
        acc[mt][nt] = __builtin_amdgcn_mfma_f32_16x16x32_bf16(
            a[mt], bfr[nt], acc[mt][nt], 0, 0, 0);
  }
#pragma unroll
  for (int nt = 0; nt < 4; ++nt) {
    int n = bn + wn + nt * 16 + t;
    float bi = b2f(bias[n]);
#pragma unroll
    for (int mt = 0; mt < 4; ++mt) {
#pragma unroll
      for (int r = 0; r < 4; ++r) {
        int m = bm + wm + mt * 16 + quad * 4 + r;
        float val = (acc[mt][nt][r] + bi) * scale;
        if (MODE == 0) {
          int s = m >> 1, b = m & 1;
          int h = n >> 6, hd = n & 63;
          ((bf16*)outv)[(((size_t)(b * HH + h)) * Sdim + s) * 64 + hd] =
              __float2bfloat16(val);
        } else {
          ((float*)outv)[(size_t)m * DD + n] = val;
        }
      }
    }
  }
}

// ---- MFMA flash attention over 64-row Q tiles, 64-key blocks ----
// GLB=0: local band rows (sblk>=1), keys = [0,64) U band; writes attnout bf16.
// GLB=1: global rows (qg), 1/16 of keys per block; writes fp32 partials.
template <int GLB>
__global__ __launch_bounds__(256) void attn_mfma(
    const bf16* __restrict__ qb, const bf16* __restrict__ kb,
    const bf16* __restrict__ vb, const int* __restrict__ kpm,
    bf16* __restrict__ attnout, float* __restrict__ part) {
  __shared__ __align__(16) u16 Qs[64][72];
  __shared__ __align__(16) u16 Ks[64][72];
  __shared__ __align__(16) u16 Vt[64][72];  // [d][key]
  __shared__ __align__(16) u16 Ps[64][72];
  __shared__ int kbadS[64];
  int bid = blockIdx.x;
  int bh, sblk = 0, seg = 0;
  if (!GLB) {
    sblk = bid & 63;
    if (sblk == 0) return;
    bh = bid >> 6;
  } else {
    bh = bid >> 4;
    seg = bid & 15;
  }
  int b = bh / HH, h = bh % HH;
  int tid = threadIdx.x, lane = tid & 63, w = tid >> 6;
  int quad = lane >> 4, t = lane & 15;
  size_t base = (size_t)bh * SS * 64;
  const u16* qp = GLB ? (const u16*)qb + (size_t)bh * GG * 64 : (const u16*)qb + base;
  const u16* kp = (const u16*)kb + base;
  const u16* vp = (const u16*)vb + base;
  int sq0 = GLB ? 0 : sblk * 64;
  {
    int row = tid >> 2, dp = (tid & 3) * 16;
#pragma unroll
    for (int i = 0; i < 4; ++i) {
      ushort4 u = *(const ushort4*)(qp + (size_t)(sq0 + row) * 64 + dp + 4 * i);
      *(ushort4*)&Qs[row][dp + 4 * i] = u;
    }
  }
  floatx4 O[4];
#pragma unroll
  for (int i = 0; i < 4; ++i) O[i] = (floatx4)(0.f);
  float pm[4] = {-3.0e38f, -3.0e38f, -3.0e38f, -3.0e38f};
  float pl[4] = {0.f, 0.f, 0.f, 0.f};
  int iters, kb_lo = 0;
  if (GLB) {
    iters = 4;
  } else {
    int win_lo = max(sq0 - WW, GG);
    int win_hi = min(sq0 + 63 + WW, SS - 1);
    kb_lo = win_lo & ~63;
    iters = ((win_hi - kb_lo) >> 6) + 2;  // +1 for the global-keys block
  }
  int srow = tid >> 2, sdp = (tid & 3) * 16;
  for (int it = 0; it < iters; ++it) {
    int kbs;
    if (GLB)
      kbs = (seg << 8) + (it << 6);
    else
      kbs = (it == 0) ? 0 : kb_lo + ((it - 1) << 6);
    ushort4 ku[4], vu[4];
#pragma unroll
    for (int i = 0; i < 4; ++i) {
      ku[i] = *(const ushort4*)(kp + (size_t)(kbs + srow) * 64 + sdp + 4 * i);
      vu[i] = *(const ushort4*)(vp + (size_t)(kbs + srow) * 64 + sdp + 4 * i);
    }
    int kbval = 0;
    if (tid < 64) kbval = kpm[b * SS + kbs + tid];
    __syncthreads();
#pragma unroll
    for (int i = 0; i < 4; ++i) {
      *(ushort4*)&Ks[srow][sdp + 4 * i] = ku[i];
      Vt[sdp + 4 * i + 0][srow] = vu[i].x;
      Vt[sdp + 4 * i + 1][srow] = vu[i].y;
      Vt[sdp + 4 * i + 2][srow] = vu[i].z;
      Vt[sdp + 4 * i + 3][srow] = vu[i].w;
    }
    if (tid < 64) kbadS[tid] = kbval;
    __syncthreads();
    // QK^T -> S (C-layout: row=quad*4+r of wave strip, col=nt*16+t)
    short8v aq[2];
#pragma unroll
    for (int ks = 0; ks < 2; ++ks)
      aq[ks] = *(const short8v*)&Qs[16 * w + t][ks * 32 + quad * 8];
    floatx4 S[4];
#pragma unroll
    for (int nt = 0; nt < 4; ++nt) {
      S[nt] = (floatx4)(0.f);
#pragma unroll
      for (int ks = 0; ks < 2; ++ks) {
        short8v bk = *(const short8v*)&Ks[nt * 16 + t][ks * 32 + quad * 8];
        S[nt] = __builtin_amdgcn_mfma_f32_16x16x32_bf16(aq[ks], bk, S[nt], 0, 0, 0);
      }
    }
    // mask + row max
    float mx[4] = {-3.0e38f, -3.0e38f, -3.0e38f, -3.0e38f};
#pragma unroll
    for (int nt = 0; nt < 4; ++nt) {
      int key = kbs + nt * 16 + t;
      int bad = kbadS[nt * 16 + t];
#pragma unroll
      for (int r = 0; r < 4; ++r) {
        bool valid;
        if (GLB) {
          valid = (bad <= 0);
        } else if (it == 0) {
          valid = true;
        } else {
          int qr = sq0 + 16 * w + quad * 4 + r;
          valid = (key >= qr - WW) && (key <= qr + WW) && (bad == 0);
        }
        if (!valid) S[nt][r] = -3.0e38f;
        mx[r] = fmaxf(mx[r], S[nt][r]);
      }
    }
#pragma unroll
    for (int r = 0; r < 4; ++r) {
#pragma unroll
      for (int off = 1; off < 16; off <<= 1) mx[r] = fmaxf(mx[r], __shfl_xor(mx[r], off));
    }
    float al[4], ps[4];
#pragma unroll
    for (int r = 0; r < 4; ++r) {
      float mnew = fmaxf(pm[r], mx[r]);
      al[r] = __expf(pm[r] - mnew);
      pm[r] = mnew;
      ps[r] = 0.f;
    }
#pragma unroll
    for (int nt = 0; nt < 4; ++nt) {
#pragma unroll
      for (int r = 0; r < 4; ++r) {
        float sv = S[nt][r];
        float p = (sv <= -1.0e37f) ? 0.f : __expf(sv - pm[r]);
        S[nt][r] = p;
        ps[r] += p;
      }
    }
#pragma unroll
    for (int r = 0; r < 4; ++r) {
#pragma unroll
      for (int off = 1; off < 16; off <<= 1) ps[r] += __shfl_xor(ps[r], off);
      pl[r] = pl[r] * al[r] + ps[r];
    }
    // P -> LDS (bf16), wave-local round trip into A-layout
#pragma unroll
    for (int nt = 0; nt < 4; ++nt)
#pragma unroll
      for (int r = 0; r < 4; ++r)
        Ps[16 * w + quad * 4 + r][nt * 16 + t] = f2bu(S[nt][r]);
#pragma unroll
    for (int dt = 0; dt < 4; ++dt)
#pragma unroll
      for (int r = 0; r < 4; ++r) O[dt][r] *= al[r];
    short8v ap[2];
#pragma unroll
    for (int ks = 0; ks < 2; ++ks)
      ap[ks] = *(const short8v*)&Ps[16 * w + t][ks * 32 + quad * 8];
#pragma unroll
    for (int dt = 0; dt < 4; ++dt) {
#pragma unroll
      for (int ks = 0; ks < 2; ++ks) {
        short8v bv = *(const short8v*)&Vt[dt * 16 + t][ks * 32 + quad * 8];
        O[dt] = __builtin_amdgcn_mfma_f32_16x16x32_bf16(ap[ks], bv, O[dt], 0, 0, 0);
      }
    }
  }
  if (!GLB) {
#pragma unroll
    for (int dt = 0; dt < 4; ++dt) {
#pragma unroll
      for (int r = 0; r < 4; ++r) {
        int qr = sq0 + 16 * w + quad * 4 + r;
        int d = dt * 16 + t;
        attnout[((size_t)qr * BB + b) * DD + h * 64 + d] =
            __float2bfloat16(O[dt][r] / pl[r]);
      }
    }
  } else {
    float* pO = part + (size_t)bid * 4224;
#pragma unroll
    for (int dt = 0; dt < 4; ++dt)
#pragma unroll
      for (int r = 0; r < 4; ++r)
        pO[(16 * w + quad * 4 + r) * 64 + dt * 16 + t] = O[dt][r];
    if (t == 0) {
#pragma unroll
      for (int r = 0; r < 4; ++r) {
        int row = 16 * w + quad * 4 + r;
        pO[4096 + row] = pm[r];
        pO[4160 + row] = pl[r];
      }
    }
  }
}

__global__ __launch_bounds__(256) void attn_comb(const float* __restrict__ part,
                                                 bf16* __restrict__ attnout) {
  int tid = threadIdx.x, lane = tid & 63, w = tid >> 6;
  int idx = blockIdx.x * 4 + w;  // [0, B*H*G)
  int bh = idx >> 6, row = idx & 63;
  int b = bh / HH, h = bh % HH;
  float M = -3.0e38f;
#pragma unroll
  for (int s16 = 0; s16 < 16; ++s16) {
    float ms = part[((size_t)(bh * 16 + s16)) * 4224 + 4096 + row];
    M = fmaxf(M, ms);
  }
  float L = 0.f, o = 0.f;
#pragma unroll
  for (int s16 = 0; s16 < 16; ++s16) {
    const float* p = part + ((size_t)(bh * 16 + s16)) * 4224;
    float sc = __expf(p[4096 + row] - M);
    o += sc * p[(row << 6) + lane];
    L += sc * p[4160 + row];
  }
  attnout[((size_t)row * BB + b) * DD + h * 64 + lane] = __float2bfloat16(o / L);
}

extern "C" void kernel_launch(void* const* d_in, const int* in_sizes, int n_in,
                              void* d_out, int out_size, void* d_ws,
                              size_t ws_size, hipStream_t stream) {
  const int* kpm = (const int*)d_in[1];
  float* outp = (float*)d_out;
  const size_t SZ = (size_t)BB * HH * SS * 64;  // 6,291,456
  const size_t WSZ = (size_t)DD * DD;           // 589,824
  bf16* p = (bf16*)d_ws;
  bf16* cQ = p; p += SZ;  // canonical query (S,B,D) bf16
  bf16* cWt[7];
  bf16* cB[7];
  for (int i = 0; i < 7; ++i) { cWt[i] = p; p += WSZ; }
  for (int i = 0; i < 7; ++i) { cB[i] = p; p += DD; }
  bf16* q = p; p += SZ;
  bf16* k = p; p += SZ;
  bf16* v = p; p += SZ;
  bf16* kg = p; p += SZ;
  bf16* vg = p; p += SZ;
  bf16* qg = p; p += (size_t)BB * HH * GG * 64;  // 98,304
  bf16* attnout = p; p += SZ;
  float* part = (float*)p;  // 384*4224 floats
  int* flag = (int*)(part + (size_t)384 * 4224);
  const float SC = 0.125f;
  dim3 blk(256);

  detect_dtype<<<1, blk, 0, stream>>>((const u16*)d_in[0], flag);
  canon_bf16<<<dim3(2048), blk, 0, stream>>>(d_in[0], cQ, (int)SZ, flag);
  for (int i = 0; i < 7; ++i) {
    transpose_w<<<dim3(24, 24), blk, 0, stream>>>(d_in[2 + 2 * i], cWt[i], flag);
    canon_bf16<<<dim3(3), blk, 0, stream>>>(d_in[3 + 2 * i], cB[i], DD, flag);
  }
  // order: q, k, v, qg, kg, vg, o
  gemm_mfma<0><<<dim3(64, 6), blk, 0, stream>>>(cQ, cWt[0], cB[0], q, SS, SC);
  gemm_mfma<0><<<dim3(64, 6), blk, 0, stream>>>(cQ, cWt[1], cB[1], k, SS, 1.f);
  gemm_mfma<0><<<dim3(64, 6), blk, 0, stream>>>(cQ, cWt[2], cB[2], v, SS, 1.f);
  gemm_mfma<0><<<dim3(64, 6), blk, 0, stream>>>(cQ, cWt[4], cB[4], kg, SS, 1.f);
  gemm_mfma<0><<<dim3(64, 6), blk, 0, stream>>>(cQ, cWt[5], cB[5], vg, SS, 1.f);
  gemm_mfma<0><<<dim3(1, 6), blk, 0, stream>>>(cQ, cWt[3], cB[3], qg, GG, SC);
  attn_mfma<0><<<dim3(BB * HH * 64), blk, 0, stream>>>(q, k, v, kpm, attnout, nullptr);
  attn_mfma<1><<<dim3(BB * HH * 16), blk, 0, stream>>>(qg, kg, vg, kpm, nullptr, part);
  attn_comb<<<dim3(BB * HH * 16), blk, 0, stream>>>(part, attnout);
  gemm_mfma<1><<<dim3(64, 6), blk, 0, stream>>>(attnout, cWt[6], cB[6], outp, 0, 1.f);
}

// Round 4
// 313.068 us; speedup vs baseline: 6.3859x; 1.2681x over previous
//
#include <hip/hip_runtime.h>
#include <hip/hip_bf16.h>
#include <cstdint>

#define BB 2
#define SS 4096
#define DD 768
#define HH 12
#define GG 64
#define WW 256

typedef __hip_bfloat16 bf16;
typedef unsigned short u16;
typedef __attribute__((ext_vector_type(8))) short short8v;
typedef __attribute__((ext_vector_type(4))) float floatx4;

__device__ __forceinline__ float b2f(u16 u) {
  return __uint_as_float(((unsigned int)u) << 16);
}
__device__ __forceinline__ u16 f2bu(float f) {
  bf16 h = __float2bfloat16(f);
  return *reinterpret_cast<u16*>(&h);
}
__device__ __forceinline__ void async_copy16(const u16* g, u16* l) {
  __builtin_amdgcn_global_load_lds(
      (const __attribute__((address_space(1))) void*)g,
      (__attribute__((address_space(3))) void*)l, 16, 0, 0);
}

struct P7 { const void* p[7]; };

// ---- dtype detect + canonicalize (inputs may be fp32 or bf16) ----
__global__ __launch_bounds__(256) void detect_dtype(const u16* __restrict__ q,
                                                    int* __restrict__ flag) {
  __shared__ int cnt;
  int tid = threadIdx.x;
  if (tid == 0) cnt = 0;
  __syncthreads();
  int bad = 0;
#pragma unroll
  for (int i = 0; i < 16; ++i) {
    float f = b2f(q[tid * 16 + i]);
    if (!isfinite(f) || fabsf(f) > 100.f) bad++;
  }
  atomicAdd(&cnt, bad);
  __syncthreads();
  if (tid == 0) *flag = (cnt > 256) ? 1 : 0;
}

__global__ __launch_bounds__(256) void canon_bf16(const void* __restrict__ src,
                                                  bf16* __restrict__ dst, int n,
                                                  const int* __restrict__ flag) {
  bool f32 = (*flag != 0);
  for (int i = blockIdx.x * 256 + threadIdx.x; i < n; i += gridDim.x * 256) {
    float v = f32 ? ((const float*)src)[i] : b2f(((const u16*)src)[i]);
    dst[i] = __float2bfloat16(v);
  }
}

// 7 weights W[K][N] -> Wt[N][K] bf16, 32x32 LDS tiles. z = which.
__global__ __launch_bounds__(256) void transpose_w7(P7 srcs, bf16* __restrict__ dst,
                                                    const int* __restrict__ flag) {
  __shared__ float tile[32][33];
  bool f32 = (*flag != 0);
  const void* src = srcs.p[blockIdx.z];
  bf16* d = dst + (size_t)blockIdx.z * DD * DD;
  int tx = threadIdx.x & 31, ty = threadIdx.x >> 5;
  int k0 = blockIdx.x * 32, n0 = blockIdx.y * 32;
#pragma unroll
  for (int i = 0; i < 32; i += 8) {
    int k = k0 + ty + i, n = n0 + tx;
    float v = f32 ? ((const float*)src)[(size_t)k * DD + n]
                  : b2f(((const u16*)src)[(size_t)k * DD + n]);
    tile[ty + i][tx] = v;
  }
  __syncthreads();
#pragma unroll
  for (int i = 0; i < 32; i += 8) {
    int n = n0 + ty + i, k = k0 + tx;
    d[(size_t)n * DD + k] = __float2bfloat16(tile[tx][ty + i]);
  }
}

__global__ __launch_bounds__(256) void canon_bias7(P7 srcs, bf16* __restrict__ dst,
                                                   const int* __restrict__ flag) {
  bool f32 = (*flag != 0);
  int which = blockIdx.x;
  const void* s = srcs.p[which];
  for (int j = threadIdx.x; j < DD; j += 256)
    dst[which * DD + j] =
        __float2bfloat16(f32 ? ((const float*)s)[j] : b2f(((const u16*)s)[j]));
}

// ---- m97-style GEMM core: 128x128 tile, BK=32, global_load_lds width 16 ----
__device__ __forceinline__ void gemm_core(const u16* __restrict__ Xp,
                                          const u16* __restrict__ Wp, int bm,
                                          int bn, int tid, u16 (*As)[32],
                                          u16 (*Bs)[32], floatx4 (&acc)[4][4]) {
  int lane = tid & 63, w = tid >> 6, quad = lane >> 4, t = lane & 15;
  int wm = (w >> 1) * 64, wn = (w & 1) * 64;
  int lr = lane >> 2, lc = (lane & 3) * 8;
  for (int k0 = 0; k0 < DD; k0 += 32) {
    __syncthreads();
#pragma unroll
    for (int i = 0; i < 2; ++i) {
      async_copy16(Xp + (size_t)(bm + w * 32 + i * 16 + lr) * DD + k0 + lc,
                   &As[w * 32 + i * 16][0]);
      async_copy16(Wp + (size_t)(bn + w * 32 + i * 16 + lr) * DD + k0 + lc,
                   &Bs[w * 32 + i * 16][0]);
    }
    __syncthreads();
    short8v a[4], bb[4];
#pragma unroll
    for (int mt = 0; mt < 4; ++mt)
      a[mt] = *(const short8v*)&As[wm + mt * 16 + t][quad * 8];
#pragma unroll
    for (int nt = 0; nt < 4; ++nt)
      bb[nt] = *(const short8v*)&Bs[wn + nt * 16 + t][quad * 8];
#pragma unroll
    for (int mt = 0; mt < 4; ++mt)
#pragma unroll
      for (int nt = 0; nt < 4; ++nt)
        acc[mt][nt] = __builtin_amdgcn_mfma_f32_16x16x32_bf16(
            a[mt], bb[nt], acc[mt][nt], 0, 0, 0);
  }
}

// Fused 5 projections: which = blockIdx.y/6 in {0:q,1:k,2:v,3:kg,4:vg}.
// v (2) and vg (4) written transposed [bh][d][s]; others heads [bh][s][d].
__global__ __launch_bounds__(256) void gemm5(const bf16* __restrict__ Xb,
                                             const bf16* __restrict__ Wt0,
                                             const bf16* __restrict__ b0,
                                             bf16* __restrict__ out0) {
  __shared__ __align__(16) u16 As[128][32];
  __shared__ __align__(16) u16 Bs[128][32];
  int tid = threadIdx.x, lane = tid & 63, w = tid >> 6, quad = lane >> 4,
      t = lane & 15;
  int wm = (w >> 1) * 64, wn = (w & 1) * 64;
  int by = blockIdx.y, which = by / 6, bn = (by % 6) * 128,
      bm = blockIdx.x * 128;
  const u16* Wp = (const u16*)Wt0 + (size_t)which * DD * DD;
  const u16* bias = (const u16*)b0 + which * DD;
  bf16* outp = out0 + (size_t)which * BB * HH * SS * 64;
  float scale = (which == 0) ? 0.125f : 1.f;
  bool tr = (which == 2) || (which == 4);
  floatx4 acc[4][4];
#pragma unroll
  for (int i = 0; i < 4; ++i)
#pragma unroll
    for (int j = 0; j < 4; ++j) acc[i][j] = (floatx4)(0.f);
  gemm_core((const u16*)Xb, Wp, bm, bn, tid, As, Bs, acc);
#pragma unroll
  for (int nt = 0; nt < 4; ++nt) {
    int n = bn + wn + nt * 16 + t;
    int h = n >> 6, hd = n & 63;
    float bi = b2f(bias[n]);
#pragma unroll
    for (int mt = 0; mt < 4; ++mt) {
#pragma unroll
      for (int r = 0; r < 4; ++r) {
        int m = bm + wm + mt * 16 + quad * 4 + r;
        int s = m >> 1, b = m & 1;
        float val = (acc[mt][nt][r] + bi) * scale;
        size_t addr = tr ? ((size_t)((b * HH + h) * 64 + hd)) * SS + s
                         : (((size_t)(b * HH + h)) * SS + s) * 64 + hd;
        outp[addr] = __float2bfloat16(val);
      }
    }
  }
}

// Single GEMM. MODE 0: bf16 heads out (Sdim rows per bh). MODE 1: fp32 flat.
template <int MODE>
__global__ __launch_bounds__(256) void gemm_one(const bf16* __restrict__ Xb,
                                                const bf16* __restrict__ Wtb,
                                                const bf16* __restrict__ biasb,
                                                void* __restrict__ outv,
                                                int Sdim, float scale) {
  __shared__ __align__(16) u16 As[128][32];
  __shared__ __align__(16) u16 Bs[128][32];
  int tid = threadIdx.x, lane = tid & 63, w = tid >> 6, quad = lane >> 4,
      t = lane & 15;
  int wm = (w >> 1) * 64, wn = (w & 1) * 64;
  int bm = blockIdx.x * 128, bn = blockIdx.y * 128;
  floatx4 acc[4][4];
#pragma unroll
  for (int i = 0; i < 4; ++i)
#pragma unroll
    for (int j = 0; j < 4; ++j) acc[i][j] = (floatx4)(0.f);
  gemm_core((const u16*)Xb, (const u16*)Wtb, bm, bn, tid, As, Bs, acc);
  const u16* bias = (const u16*)biasb;
#pragma unroll
  for (int nt = 0; nt < 4; ++nt) {
    int n = bn + wn + nt * 16 + t;
    float bi = b2f(bias[n]);
#pragma unroll
    for (int mt = 0; mt < 4; ++mt) {
#pragma unroll
      for (int r = 0; r < 4; ++r) {
        int m = bm + wm + mt * 16 + quad * 4 + r;
        float val = (acc[mt][nt][r] + bi) * scale;
        if (MODE == 0) {
          int s = m >> 1, b = m & 1;
          int h = n >> 6, hd = n & 63;
          ((bf16*)outv)[(((size_t)(b * HH + h)) * Sdim + s) * 64 + hd] =
              __float2bfloat16(val);
        } else {
          ((float*)outv)[(size_t)m * DD + n] = val;
        }
      }
    }
  }
}

// ---- MFMA flash attention, single-pass softmax (scores bounded ~|3|) ----
// GLB=0: local rows, keys = [0,64) U band; v input transposed [bh][d][s].
// GLB=1: global rows, 256-key segment per block; writes fp32 partials (O,l).
template <int GLB>
__global__ __launch_bounds__(256) void attn_mfma(
    const bf16* __restrict__ qb, const bf16* __restrict__ kb,
    const bf16* __restrict__ vtb, const int* __restrict__ kpm,
    bf16* __restrict__ attnout, float* __restrict__ part) {
  __shared__ __align__(16) u16 Qs[64][72];
  __shared__ __align__(16) u16 Ks[64][72];
  __shared__ __align__(16) u16 Vt[64][72];  // [d][key]
  __shared__ __align__(16) u16 Ps[64][72];  // col ^= quad<<4 swizzle
  __shared__ int kbadS[64];
  int bid = blockIdx.x;
  int bh, sblk = 0, seg = 0;
  if (!GLB) {
    sblk = bid & 63;
    if (sblk == 0) return;
    bh = bid >> 6;
  } else {
    bh = bid >> 4;
    seg = bid & 15;
  }
  int b = bh / HH, h = bh % HH;
  int tid = threadIdx.x, lane = tid & 63, w = tid >> 6;
  int quad = lane >> 4, t = lane & 15;
  const u16* qp = GLB ? (const u16*)qb + (size_t)bh * GG * 64
                      : (const u16*)qb + (size_t)bh * SS * 64;
  const u16* kp = (const u16*)kb + (size_t)bh * SS * 64;
  const u16* vp = (const u16*)vtb + (size_t)bh * SS * 64;  // rows are d
  int sq0 = GLB ? 0 : sblk * 64;
  int srow = tid >> 2, scol = (tid & 3) * 16;
#pragma unroll
  for (int i = 0; i < 4; ++i)
    *(ushort4*)&Qs[srow][scol + 4 * i] =
        *(const ushort4*)(qp + (size_t)(sq0 + srow) * 64 + scol + 4 * i);
  __syncthreads();
  short8v aq[2];
#pragma unroll
  for (int ks = 0; ks < 2; ++ks)
    aq[ks] = *(const short8v*)&Qs[16 * w + t][ks * 32 + quad * 8];
  floatx4 O[4];
#pragma unroll
  for (int i = 0; i < 4; ++i) O[i] = (floatx4)(0.f);
  float ps[4] = {0.f, 0.f, 0.f, 0.f};
  int iters, kb_lo = 0;
  if (GLB) {
    iters = 4;
  } else {
    int win_lo = max(sq0 - WW, GG);
    int win_hi = min(sq0 + 63 + WW, SS - 1);
    kb_lo = win_lo & ~63;
    iters = ((win_hi - kb_lo) >> 6) + 2;  // +1: global-keys block
  }
  for (int it = 0; it < iters; ++it) {
    int kbs = GLB ? (seg << 8) + (it << 6)
                  : ((it == 0) ? 0 : kb_lo + ((it - 1) << 6));
    ushort4 ku[4], vu[4];
#pragma unroll
    for (int i = 0; i < 4; ++i) {
      ku[i] = *(const ushort4*)(kp + (size_t)(kbs + srow) * 64 + scol + 4 * i);
      vu[i] = *(const ushort4*)(vp + (size_t)srow * SS + kbs + scol + 4 * i);
    }
    int kbval = (tid < 64) ? kpm[b * SS + kbs + tid] : 0;
    __syncthreads();
#pragma unroll
    for (int i = 0; i < 4; ++i) {
      *(ushort4*)&Ks[srow][scol + 4 * i] = ku[i];
      *(ushort4*)&Vt[srow][scol + 4 * i] = vu[i];
    }
    if (tid < 64) kbadS[tid] = kbval;
    __syncthreads();
    floatx4 S[4];
#pragma unroll
    for (int nt = 0; nt < 4; ++nt) {
      S[nt] = (floatx4)(0.f);
#pragma unroll
      for (int ks = 0; ks < 2; ++ks) {
        short8v bk = *(const short8v*)&Ks[nt * 16 + t][ks * 32 + quad * 8];
        S[nt] = __builtin_amdgcn_mfma_f32_16x16x32_bf16(aq[ks], bk, S[nt], 0, 0, 0);
      }
    }
    if (GLB) {
#pragma unroll
      for (int nt = 0; nt < 4; ++nt) {
        int bad = kbadS[nt * 16 + t];
#pragma unroll
        for (int r = 0; r < 4; ++r) {
          float p = __expf((bad <= 0) ? S[nt][r] : -3.0e38f);
          ps[r] += p;
          Ps[16 * w + quad * 4 + r][((nt ^ quad) << 4) + t] = f2bu(p);
        }
      }
    } else if (it == 0) {
#pragma unroll
      for (int nt = 0; nt < 4; ++nt)
#pragma unroll
        for (int r = 0; r < 4; ++r) {
          float p = __expf(S[nt][r]);
          ps[r] += p;
          Ps[16 * w + quad * 4 + r][((nt ^ quad) << 4) + t] = f2bu(p);
        }
    } else {
#pragma unroll
      for (int r = 0; r < 4; ++r) {
        int qr = sq0 + 16 * w + quad * 4 + r;
        int off = kbs + t + WW - qr;  // key - (qr-W) at nt=0
#pragma unroll
        for (int nt = 0; nt < 4; ++nt) {
          int bad = kbadS[nt * 16 + t];
          unsigned u = (unsigned)(off + nt * 16);
          float p = __expf((u <= 2 * WW && bad == 0) ? S[nt][r] : -3.0e38f);
          ps[r] += p;
          Ps[16 * w + quad * 4 + r][((nt ^ quad) << 4) + t] = f2bu(p);
        }
      }
    }
    short8v ap[2];
#pragma unroll
    for (int ks = 0; ks < 2; ++ks) {
      int chunk = (2 * ks + (quad >> 1)) ^ ((t >> 2) & 3);
      ap[ks] = *(const short8v*)&Ps[16 * w + t][(chunk << 4) + ((quad & 1) << 3)];
    }
#pragma unroll
    for (int dt = 0; dt < 4; ++dt)
#pragma unroll
      for (int ks = 0; ks < 2; ++ks) {
        short8v bv = *(const short8v*)&Vt[dt * 16 + t][ks * 32 + quad * 8];
        O[dt] = __builtin_amdgcn_mfma_f32_16x16x32_bf16(ap[ks], bv, O[dt], 0, 0, 0);
      }
  }
#pragma unroll
  for (int r = 0; r < 4; ++r)
#pragma unroll
    for (int off = 1; off < 16; off <<= 1) ps[r] += __shfl_xor(ps[r], off);
  if (!GLB) {
#pragma unroll
    for (int dt = 0; dt < 4; ++dt)
#pragma unroll
      for (int r = 0; r < 4; ++r) {
        int qr = sq0 + 16 * w + quad * 4 + r;
        attnout[((size_t)qr * BB + b) * DD + h * 64 + dt * 16 + t] =
            __float2bfloat16(O[dt][r] / ps[r]);
      }
  } else {
    float* pO = part + (size_t)bid * 4160;
#pragma unroll
    for (int dt = 0; dt < 4; ++dt)
#pragma unroll
      for (int r = 0; r < 4; ++r)
        pO[(16 * w + quad * 4 + r) * 64 + dt * 16 + t] = O[dt][r];
    if (t == 0)
#pragma unroll
      for (int r = 0; r < 4; ++r) pO[4096 + 16 * w + quad * 4 + r] = ps[r];
  }
}

__global__ __launch_bounds__(256) void attn_comb(const float* __restrict__ part,
                                                 bf16* __restrict__ attnout) {
  int tid = threadIdx.x, lane = tid & 63, w = tid >> 6;
  int idx = blockIdx.x * 4 + w;  // [0, B*H*64)
  int bh = idx >> 6, row = idx & 63;
  int b = bh / HH, h = bh % HH;
  float o = 0.f, L = 0.f;
#pragma unroll
  for (int s16 = 0; s16 < 16; ++s16) {
    const float* p = part + (size_t)(bh * 16 + s16) * 4160;
    o += p[(row << 6) + lane];
    L += p[4096 + row];
  }
  attnout[((size_t)row * BB + b) * DD + h * 64 + lane] = __float2bfloat16(o / L);
}

extern "C" void kernel_launch(void* const* d_in, const int* in_sizes, int n_in,
                              void* d_out, int out_size, void* d_ws,
                              size_t ws_size, hipStream_t stream) {
  const int* kpm = (const int*)d_in[1];
  float* outp = (float*)d_out;
  const size_t SZ = (size_t)BB * HH * SS * 64;  // 6,291,456
  const size_t WSZ = (size_t)DD * DD;           // 589,824
  bf16* p = (bf16*)d_ws;
  bf16* cQ = p; p += SZ;
  bf16* cWt = p; p += 7 * WSZ;  // slots: q,k,v,kg,vg,qg,o
  bf16* cB = p; p += 7 * DD;
  bf16* q = p; p += SZ;   // heads [bh][s][d]
  bf16* k = p; p += SZ;   // heads
  bf16* v = p; p += SZ;   // TRANSPOSED [bh][d][s]
  bf16* kg = p; p += SZ;  // heads
  bf16* vg = p; p += SZ;  // TRANSPOSED
  bf16* qg = p; p += (size_t)BB * HH * GG * 64;
  bf16* attnout = p; p += SZ;
  float* part = (float*)p;  // 384 * 4160 floats
  int* flag = (int*)(part + (size_t)384 * 4160);
  const float SC = 0.125f;
  dim3 blk(256);

  P7 wsrc{{d_in[2], d_in[4], d_in[6], d_in[10], d_in[12], d_in[8], d_in[14]}};
  P7 bsrc{{d_in[3], d_in[5], d_in[7], d_in[11], d_in[13], d_in[9], d_in[15]}};

  detect_dtype<<<1, blk, 0, stream>>>((const u16*)d_in[0], flag);
  canon_bf16<<<dim3(2048), blk, 0, stream>>>(d_in[0], cQ, (int)SZ, flag);
  transpose_w7<<<dim3(24, 24, 7), blk, 0, stream>>>(wsrc, cWt, flag);
  canon_bias7<<<dim3(7), blk, 0, stream>>>(bsrc, cB, flag);

  gemm5<<<dim3(64, 30), blk, 0, stream>>>(cQ, cWt, cB, q);
  gemm_one<0><<<dim3(1, 6), blk, 0, stream>>>(cQ, cWt + 5 * WSZ, cB + 5 * DD,
                                              qg, GG, SC);
  attn_mfma<0><<<dim3(BB * HH * 64), blk, 0, stream>>>(q, k, v, kpm, attnout,
                                                       nullptr);
  attn_mfma<1><<<dim3(BB * HH * 16), blk, 0, stream>>>(qg, kg, vg, kpm, nullptr,
                                                       part);
  attn_comb<<<dim3(BB * HH * 16), blk, 0, stream>>>(part, attnout);
  gemm_one<1><<<dim3(64, 6), blk, 0, stream>>>(attnout, cWt + 6 * WSZ,
                                               cB + 6 * DD, outp, 0, 1.f);
}

// Round 5
// 304.377 us; speedup vs baseline: 6.5682x; 1.0286x over previous
//
#include <hip/hip_runtime.h>
#include <hip/hip_bf16.h>
#include <cstdint>

#define BB 2
#define SS 4096
#define DD 768
#define HH 12
#define GG 64
#define WW 256

typedef __hip_bfloat16 bf16;
typedef unsigned short u16;
typedef __attribute__((ext_vector_type(8))) short short8v;
typedef __attribute__((ext_vector_type(4))) float floatx4;

__device__ __forceinline__ float b2f(u16 u) {
  return __uint_as_float(((unsigned int)u) << 16);
}
__device__ __forceinline__ u16 f2bu(float f) {
  bf16 h = __float2bfloat16(f);
  return *reinterpret_cast<u16*>(&h);
}
__device__ __forceinline__ void async_copy16(const u16* g, u16* l) {
  __builtin_amdgcn_global_load_lds(
      (const __attribute__((address_space(1))) void*)g,
      (__attribute__((address_space(3))) void*)l, 16, 0, 0);
}

struct P7 { const void* p[7]; };

// ---- dtype detect + canonicalize (inputs may be fp32 or bf16) ----
__global__ __launch_bounds__(256) void detect_dtype(const u16* __restrict__ q,
                                                    int* __restrict__ flag) {
  __shared__ int cnt;
  int tid = threadIdx.x;
  if (tid == 0) cnt = 0;
  __syncthreads();
  int bad = 0;
#pragma unroll
  for (int i = 0; i < 16; ++i) {
    float f = b2f(q[tid * 16 + i]);
    if (!isfinite(f) || fabsf(f) > 100.f) bad++;
  }
  atomicAdd(&cnt, bad);
  __syncthreads();
  if (tid == 0) *flag = (cnt > 256) ? 1 : 0;
}

__global__ __launch_bounds__(256) void canon_bf16(const void* __restrict__ src,
                                                  bf16* __restrict__ dst, int n,
                                                  const int* __restrict__ flag) {
  bool f32 = (*flag != 0);
  for (int i = blockIdx.x * 256 + threadIdx.x; i < n; i += gridDim.x * 256) {
    float v = f32 ? ((const float*)src)[i] : b2f(((const u16*)src)[i]);
    dst[i] = __float2bfloat16(v);
  }
}

// 7 weights W[K][N] -> Wt[N][K] bf16, 32x32 LDS tiles. z = which.
__global__ __launch_bounds__(256) void transpose_w7(P7 srcs, bf16* __restrict__ dst,
                                                    const int* __restrict__ flag) {
  __shared__ float tile[32][33];
  bool f32 = (*flag != 0);
  const void* src = srcs.p[blockIdx.z];
  bf16* d = dst + (size_t)blockIdx.z * DD * DD;
  int tx = threadIdx.x & 31, ty = threadIdx.x >> 5;
  int k0 = blockIdx.x * 32, n0 = blockIdx.y * 32;
#pragma unroll
  for (int i = 0; i < 32; i += 8) {
    int k = k0 + ty + i, n = n0 + tx;
    float v = f32 ? ((const float*)src)[(size_t)k * DD + n]
                  : b2f(((const u16*)src)[(size_t)k * DD + n]);
    tile[ty + i][tx] = v;
  }
  __syncthreads();
#pragma unroll
  for (int i = 0; i < 32; i += 8) {
    int n = n0 + ty + i, k = k0 + tx;
    d[(size_t)n * DD + k] = __float2bfloat16(tile[tx][ty + i]);
  }
}

__global__ __launch_bounds__(256) void canon_bias7(P7 srcs, bf16* __restrict__ dst,
                                                   const int* __restrict__ flag) {
  bool f32 = (*flag != 0);
  int which = blockIdx.x;
  const void* s = srcs.p[which];
  for (int j = threadIdx.x; j < DD; j += 256)
    dst[which * DD + j] =
        __float2bfloat16(f32 ? ((const float*)s)[j] : b2f(((const u16*)s)[j]));
}

// Heads [bh][s][d] -> [bh][d][s] transpose, 64x64 tiles.
__global__ __launch_bounds__(256) void tr_vt(const bf16* __restrict__ src,
                                             bf16* __restrict__ dst) {
  __shared__ u16 T[64][66];
  int stile = blockIdx.x, bh = blockIdx.y;
  const u16* in = (const u16*)src + (size_t)bh * SS * 64;
  u16* out = (u16*)dst + (size_t)bh * SS * 64;
  int tid = threadIdx.x;
  int srow = tid >> 2, scol = (tid & 3) * 16;
#pragma unroll
  for (int i = 0; i < 4; ++i) {
    ushort4 u = *(const ushort4*)(in + (size_t)(stile * 64 + srow) * 64 + scol + 4 * i);
    *(ushort2*)&T[srow][scol + 4 * i] = make_ushort2(u.x, u.y);
    *(ushort2*)&T[srow][scol + 4 * i + 2] = make_ushort2(u.z, u.w);
  }
  __syncthreads();
  int drow = tid >> 2, dcol = (tid & 3) * 16;  // drow = d, dcol = s chunk
#pragma unroll
  for (int i = 0; i < 4; ++i) {
    ushort4 u;
    u.x = T[dcol + 4 * i + 0][drow];
    u.y = T[dcol + 4 * i + 1][drow];
    u.z = T[dcol + 4 * i + 2][drow];
    u.w = T[dcol + 4 * i + 3][drow];
    *(ushort4*)(out + (size_t)drow * SS + stile * 64 + dcol + 4 * i) = u;
  }
}

// ---- GEMM core: 128x128 tile, BK=32, async staging, SWAPPED operands ----
// acc[nt][mt][r] = C[m = bm+wm+mt*16+t][n = bn+wn+nt*16+quad*4+r]
__device__ __forceinline__ void gemm_core(const u16* __restrict__ Xp,
                                          const u16* __restrict__ Wp, int bm,
                                          int bn, int tid, u16 (*As)[32],
                                          u16 (*Bs)[32], floatx4 (&acc)[4][4]) {
  int lane = tid & 63, w = tid >> 6, quad = lane >> 4, t = lane & 15;
  int wm = (w >> 1) * 64, wn = (w & 1) * 64;
  int lr = lane >> 2, lc = (lane & 3) * 8;
  for (int k0 = 0; k0 < DD; k0 += 32) {
    __syncthreads();
#pragma unroll
    for (int i = 0; i < 2; ++i) {
      async_copy16(Xp + (size_t)(bm + w * 32 + i * 16 + lr) * DD + k0 + lc,
                   &As[w * 32 + i * 16][0]);
      async_copy16(Wp + (size_t)(bn + w * 32 + i * 16 + lr) * DD + k0 + lc,
                   &Bs[w * 32 + i * 16][0]);
    }
    __syncthreads();
    short8v a[4], bb[4];
#pragma unroll
    for (int mt = 0; mt < 4; ++mt)
      a[mt] = *(const short8v*)&As[wm + mt * 16 + t][quad * 8];
#pragma unroll
    for (int nt = 0; nt < 4; ++nt)
      bb[nt] = *(const short8v*)&Bs[wn + nt * 16 + t][quad * 8];
#pragma unroll
    for (int nt = 0; nt < 4; ++nt)
#pragma unroll
      for (int mt = 0; mt < 4; ++mt)
        acc[nt][mt] = __builtin_amdgcn_mfma_f32_16x16x32_bf16(
            bb[nt], a[mt], acc[nt][mt], 0, 0, 0);
  }
}

// Fused 5 projections, all heads layout [bh][s][d]. which=blockIdx.y/6.
__global__ __launch_bounds__(256, 3) void gemm5(const bf16* __restrict__ Xb,
                                                const bf16* __restrict__ Wt0,
                                                const bf16* __restrict__ b0,
                                                bf16* __restrict__ out0) {
  __shared__ __align__(16) u16 As[128][32];
  __shared__ __align__(16) u16 Bs[128][32];
  int tid = threadIdx.x, lane = tid & 63, w = tid >> 6, quad = lane >> 4,
      t = lane & 15;
  int wm = (w >> 1) * 64, wn = (w & 1) * 64;
  int by = blockIdx.y, which = by / 6, bn = (by % 6) * 128,
      bm = blockIdx.x * 128;
  const u16* Wp = (const u16*)Wt0 + (size_t)which * DD * DD;
  const u16* bias = (const u16*)b0 + which * DD;
  bf16* outp = out0 + (size_t)which * BB * HH * SS * 64;
  float scale = (which == 0) ? 0.125f : 1.f;
  floatx4 acc[4][4];
#pragma unroll
  for (int i = 0; i < 4; ++i)
#pragma unroll
    for (int j = 0; j < 4; ++j) acc[i][j] = (floatx4)(0.f);
  gemm_core((const u16*)Xb, Wp, bm, bn, tid, As, Bs, acc);
#pragma unroll
  for (int nt = 0; nt < 4; ++nt) {
    int n0 = bn + wn + nt * 16 + quad * 4;
    int h = n0 >> 6, hd0 = n0 & 63;
    ushort4 bi4 = *(const ushort4*)&bias[n0];
    float bia[4] = {b2f(bi4.x), b2f(bi4.y), b2f(bi4.z), b2f(bi4.w)};
#pragma unroll
    for (int mt = 0; mt < 4; ++mt) {
      int m = bm + wm + mt * 16 + t;
      int s = m >> 1, b = m & 1;
      ushort4 o;
      o.x = f2bu((acc[nt][mt][0] + bia[0]) * scale);
      o.y = f2bu((acc[nt][mt][1] + bia[1]) * scale);
      o.z = f2bu((acc[nt][mt][2] + bia[2]) * scale);
      o.w = f2bu((acc[nt][mt][3] + bia[3]) * scale);
      *(ushort4*)((u16*)outp + (((size_t)(b * HH + h)) * SS + s) * 64 + hd0) = o;
    }
  }
}

// Single GEMM. MODE 0: bf16 heads out (Sdim rows per bh). MODE 1: fp32 flat.
template <int MODE>
__global__ __launch_bounds__(256, 3) void gemm_one(const bf16* __restrict__ Xb,
                                                   const bf16* __restrict__ Wtb,
                                                   const bf16* __restrict__ biasb,
                                                   void* __restrict__ outv,
                                                   int Sdim, float scale) {
  __shared__ __align__(16) u16 As[128][32];
  __shared__ __align__(16) u16 Bs[128][32];
  int tid = threadIdx.x, lane = tid & 63, w = tid >> 6, quad = lane >> 4,
      t = lane & 15;
  int wm = (w >> 1) * 64, wn = (w & 1) * 64;
  int bm = blockIdx.x * 128, bn = blockIdx.y * 128;
  floatx4 acc[4][4];
#pragma unroll
  for (int i = 0; i < 4; ++i)
#pragma unroll
    for (int j = 0; j < 4; ++j) acc[i][j] = (floatx4)(0.f);
  gemm_core((const u16*)Xb, (const u16*)Wtb, bm, bn, tid, As, Bs, acc);
  const u16* bias = (const u16*)biasb;
#pragma unroll
  for (int nt = 0; nt < 4; ++nt) {
    int n0 = bn + wn + nt * 16 + quad * 4;
    ushort4 bi4 = *(const ushort4*)&bias[n0];
    float bia[4] = {b2f(bi4.x), b2f(bi4.y), b2f(bi4.z), b2f(bi4.w)};
#pragma unroll
    for (int mt = 0; mt < 4; ++mt) {
      int m = bm + wm + mt * 16 + t;
      if (MODE == 0) {
        int s = m >> 1, b = m & 1;
        int h = n0 >> 6, hd0 = n0 & 63;
        ushort4 o;
        o.x = f2bu((acc[nt][mt][0] + bia[0]) * scale);
        o.y = f2bu((acc[nt][mt][1] + bia[1]) * scale);
        o.z = f2bu((acc[nt][mt][2] + bia[2]) * scale);
        o.w = f2bu((acc[nt][mt][3] + bia[3]) * scale);
        *(ushort4*)((u16*)outv + (((size_t)(b * HH + h)) * Sdim + s) * 64 + hd0) = o;
      } else {
        float4 o;
        o.x = (acc[nt][mt][0] + bia[0]) * scale;
        o.y = (acc[nt][mt][1] + bia[1]) * scale;
        o.z = (acc[nt][mt][2] + bia[2]) * scale;
        o.w = (acc[nt][mt][3] + bia[3]) * scale;
        *(float4*)((float*)outv + (size_t)m * DD + n0) = o;
      }
    }
  }
}

// ---- MFMA flash attention, 128-row Q tiles, async staging, swapped PV ----
__global__ __launch_bounds__(256, 3) void attn_local128(
    const bf16* __restrict__ qb, const bf16* __restrict__ kb,
    const bf16* __restrict__ vtb, const int* __restrict__ kpm,
    bf16* __restrict__ attnout) {
  __shared__ __align__(16) u16 Qs[128][64];
  __shared__ __align__(16) u16 Ks[64][64];
  __shared__ __align__(16) u16 Vt[64][64];  // [d][key]
  __shared__ __align__(16) u16 Ps[128][72];  // swizzled
  __shared__ float Ls[128];
  __shared__ int kbadS[64];
  int bid = blockIdx.x;
  int tile = bid & 31, bh = bid >> 5;
  int b = bh / HH, h = bh % HH;
  int tid = threadIdx.x, lane = tid & 63, w = tid >> 6;
  int quad = lane >> 4, t = lane & 15;
  const u16* qp = (const u16*)qb + (size_t)bh * SS * 64;
  const u16* kp = (const u16*)kb + (size_t)bh * SS * 64;
  const u16* vp = (const u16*)vtb + (size_t)bh * SS * 64;  // rows are d
  int sq0 = GG + tile * 128;
  // Q staging (rows clamped to SS-1 for the half-valid last tile)
#pragma unroll
  for (int j = 0; j < 4; ++j) {
    int qr = sq0 + w * 32 + j * 8 + (lane >> 3);
    int sr = qr < SS ? qr : SS - 1;
    async_copy16(qp + (size_t)sr * 64 + (lane & 7) * 8, &Qs[w * 32 + j * 8][0]);
  }
  __syncthreads();
  short8v aq[2][2];
#pragma unroll
  for (int st = 0; st < 2; ++st)
#pragma unroll
    for (int ks = 0; ks < 2; ++ks)
      aq[st][ks] = *(const short8v*)&Qs[w * 32 + st * 16 + t][ks * 32 + quad * 8];
  floatx4 O[2][4];
#pragma unroll
  for (int st = 0; st < 2; ++st)
#pragma unroll
    for (int dt = 0; dt < 4; ++dt) O[st][dt] = (floatx4)(0.f);
  float ps[2][4] = {};
  int win_lo = max(sq0 - WW, GG);
  int win_hi = min(sq0 + 127 + WW, SS - 1);
  int kb_lo = win_lo & ~63;
  int iters = ((win_hi - kb_lo) >> 6) + 2;  // +1: global-keys block
  for (int it = 0; it < iters; ++it) {
    int kbs = (it == 0) ? 0 : kb_lo + ((it - 1) << 6);
    __syncthreads();
#pragma unroll
    for (int j = 0; j < 2; ++j) {
      async_copy16(kp + (size_t)(kbs + w * 16 + j * 8 + (lane >> 3)) * 64 +
                       (lane & 7) * 8,
                   &Ks[w * 16 + j * 8][0]);
      async_copy16(vp + (size_t)(w * 16 + j * 8 + (lane >> 3)) * SS + kbs +
                       (lane & 7) * 8,
                   &Vt[w * 16 + j * 8][0]);
    }
    if (tid < 64) kbadS[tid] = kpm[b * SS + kbs + tid];
    __syncthreads();
#pragma unroll
    for (int st = 0; st < 2; ++st) {
      floatx4 S[4];
#pragma unroll
      for (int nt = 0; nt < 4; ++nt) {
        S[nt] = (floatx4)(0.f);
#pragma unroll
        for (int ks = 0; ks < 2; ++ks) {
          short8v bk = *(const short8v*)&Ks[nt * 16 + t][ks * 32 + quad * 8];
          S[nt] = __builtin_amdgcn_mfma_f32_16x16x32_bf16(aq[st][ks], bk, S[nt],
                                                          0, 0, 0);
        }
      }
      int prow = w * 32 + st * 16 + quad * 4;
      if (it == 0) {
#pragma unroll
        for (int nt = 0; nt < 4; ++nt)
#pragma unroll
          for (int r = 0; r < 4; ++r) {
            float p = __expf(S[nt][r]);
            ps[st][r] += p;
            Ps[prow + r][((nt ^ quad) << 4) + t] = f2bu(p);
          }
      } else {
#pragma unroll
        for (int r = 0; r < 4; ++r) {
          int qr = sq0 + prow + r;
          int off = kbs + t + WW - qr;
#pragma unroll
          for (int nt = 0; nt < 4; ++nt) {
            int bad = kbadS[nt * 16 + t];
            unsigned u = (unsigned)(off + nt * 16);
            float p = __expf((u <= 2 * WW && bad == 0) ? S[nt][r] : -3.0e38f);
            ps[st][r] += p;
            Ps[prow + r][((nt ^ quad) << 4) + t] = f2bu(p);
          }
        }
      }
    }
    // PV: O[d][q] += Vt-frag (A) * P-frag (B)
    short8v ap[2][2];
#pragma unroll
    for (int st = 0; st < 2; ++st)
#pragma unroll
      for (int ks = 0; ks < 2; ++ks) {
        int chunk = (2 * ks + (quad >> 1)) ^ ((t >> 2) & 3);
        ap[st][ks] = *(const short8v*)&Ps[w * 32 + st * 16 + t]
                                        [(chunk << 4) + ((quad & 1) << 3)];
      }
#pragma unroll
    for (int dt = 0; dt < 4; ++dt) {
#pragma unroll
      for (int ks = 0; ks < 2; ++ks) {
        short8v av = *(const short8v*)&Vt[dt * 16 + t][ks * 32 + quad * 8];
#pragma unroll
        for (int st = 0; st < 2; ++st)
          O[st][dt] = __builtin_amdgcn_mfma_f32_16x16x32_bf16(av, ap[st][ks],
                                                              O[st][dt], 0, 0, 0);
      }
    }
  }
#pragma unroll
  for (int st = 0; st < 2; ++st) {
#pragma unroll
    for (int r = 0; r < 4; ++r)
#pragma unroll
      for (int off = 1; off < 16; off <<= 1) ps[st][r] += __shfl_xor(ps[st][r], off);
    if (t == 0)
#pragma unroll
      for (int r = 0; r < 4; ++r) Ls[w * 32 + st * 16 + quad * 4 + r] = ps[st][r];
  }
#pragma unroll
  for (int st = 0; st < 2; ++st) {
    int q = sq0 + w * 32 + st * 16 + t;
    if (q < SS) {
      float linv = 1.0f / Ls[w * 32 + st * 16 + t];
#pragma unroll
      for (int dt = 0; dt < 4; ++dt) {
        ushort4 o;
        o.x = f2bu(O[st][dt][0] * linv);
        o.y = f2bu(O[st][dt][1] * linv);
        o.z = f2bu(O[st][dt][2] * linv);
        o.w = f2bu(O[st][dt][3] * linv);
        *(ushort4*)((u16*)attnout + ((size_t)q * BB + b) * DD + h * 64 +
                    dt * 16 + quad * 4) = o;
      }
    }
  }
}

// Global-row attention (rows < G), 256-key segment per block; fp32 partials.
__global__ __launch_bounds__(256) void attn_glb(
    const bf16* __restrict__ qgb, const bf16* __restrict__ kgb,
    const bf16* __restrict__ vtb, const int* __restrict__ kpm,
    float* __restrict__ part) {
  __shared__ __align__(16) u16 Qs[64][72];
  __shared__ __align__(16) u16 Ks[64][72];
  __shared__ __align__(16) u16 Vt[64][72];
  __shared__ __align__(16) u16 Ps[64][72];
  __shared__ int kbadS[64];
  int bid = blockIdx.x;
  int bh = bid >> 4, seg = bid & 15;
  int b = bh / HH;
  int tid = threadIdx.x, lane = tid & 63, w = tid >> 6;
  int quad = lane >> 4, t = lane & 15;
  const u16* qp = (const u16*)qgb + (size_t)bh * GG * 64;
  const u16* kp = (const u16*)kgb + (size_t)bh * SS * 64;
  const u16* vp = (const u16*)vtb + (size_t)bh * SS * 64;  // rows are d
  int srow = tid >> 2, scol = (tid & 3) * 16;
#pragma unroll
  for (int i = 0; i < 4; ++i)
    *(ushort4*)&Qs[srow][scol + 4 * i] =
        *(const ushort4*)(qp + (size_t)srow * 64 + scol + 4 * i);
  __syncthreads();
  short8v aq[2];
#pragma unroll
  for (int ks = 0; ks < 2; ++ks)
    aq[ks] = *(const short8v*)&Qs[16 * w + t][ks * 32 + quad * 8];
  floatx4 O[4];
#pragma unroll
  for (int i = 0; i < 4; ++i) O[i] = (floatx4)(0.f);
  float ps[4] = {0.f, 0.f, 0.f, 0.f};
  for (int it = 0; it < 4; ++it) {
    int kbs = (seg << 8) + (it << 6);
    ushort4 ku[4], vu[4];
#pragma unroll
    for (int i = 0; i < 4; ++i) {
      ku[i] = *(const ushort4*)(kp + (size_t)(kbs + srow) * 64 + scol + 4 * i);
      vu[i] = *(const ushort4*)(vp + (size_t)srow * SS + kbs + scol + 4 * i);
    }
    int kbval = (tid < 64) ? kpm[b * SS + kbs + tid] : 0;
    __syncthreads();
#pragma unroll
    for (int i = 0; i < 4; ++i) {
      *(ushort4*)&Ks[srow][scol + 4 * i] = ku[i];
      *(ushort4*)&Vt[srow][scol + 4 * i] = vu[i];
    }
    if (tid < 64) kbadS[tid] = kbval;
    __syncthreads();
    floatx4 S[4];
#pragma unroll
    for (int nt = 0; nt < 4; ++nt) {
      S[nt] = (floatx4)(0.f);
#pragma unroll
      for (int ks = 0; ks < 2; ++ks) {
        short8v bk = *(const short8v*)&Ks[nt * 16 + t][ks * 32 + quad * 8];
        S[nt] = __builtin_amdgcn_mfma_f32_16x16x32_bf16(aq[ks], bk, S[nt], 0, 0, 0);
      }
    }
#pragma unroll
    for (int nt = 0; nt < 4; ++nt) {
      int bad = kbadS[nt * 16 + t];
#pragma unroll
      for (int r = 0; r < 4; ++r) {
        float p = __expf((bad <= 0) ? S[nt][r] : -3.0e38f);
        ps[r] += p;
        Ps[16 * w + quad * 4 + r][((nt ^ quad) << 4) + t] = f2bu(p);
      }
    }
    short8v ap[2];
#pragma unroll
    for (int ks = 0; ks < 2; ++ks) {
      int chunk = (2 * ks + (quad >> 1)) ^ ((t >> 2) & 3);
      ap[ks] = *(const short8v*)&Ps[16 * w + t][(chunk << 4) + ((quad & 1) << 3)];
    }
#pragma unroll
    for (int dt = 0; dt < 4; ++dt)
#pragma unroll
      for (int ks = 0; ks < 2; ++ks) {
        short8v bv = *(const short8v*)&Vt[dt * 16 + t][ks * 32 + quad * 8];
        O[dt] = __builtin_amdgcn_mfma_f32_16x16x32_bf16(ap[ks], bv, O[dt], 0, 0, 0);
      }
  }
#pragma unroll
  for (int r = 0; r < 4; ++r)
#pragma unroll
    for (int off = 1; off < 16; off <<= 1) ps[r] += __shfl_xor(ps[r], off);
  float* pO = part + (size_t)bid * 4160;
#pragma unroll
  for (int dt = 0; dt < 4; ++dt)
#pragma unroll
    for (int r = 0; r < 4; ++r)
      pO[(16 * w + quad * 4 + r) * 64 + dt * 16 + t] = O[dt][r];
  if (t == 0)
#pragma unroll
    for (int r = 0; r < 4; ++r) pO[4096 + 16 * w + quad * 4 + r] = ps[r];
}

__global__ __launch_bounds__(256) void attn_comb(const float* __restrict__ part,
                                                 bf16* __restrict__ attnout) {
  int tid = threadIdx.x, lane = tid & 63, w = tid >> 6;
  int idx = blockIdx.x * 4 + w;  // [0, B*H*64)
  int bh = idx >> 6, row = idx & 63;
  int b = bh / HH, h = bh % HH;
  float o = 0.f, L = 0.f;
#pragma unroll
  for (int s16 = 0; s16 < 16; ++s16) {
    const float* p = part + (size_t)(bh * 16 + s16) * 4160;
    o += p[(row << 6) + lane];
    L += p[4096 + row];
  }
  attnout[((size_t)row * BB + b) * DD + h * 64 + lane] = __float2bfloat16(o / L);
}

extern "C" void kernel_launch(void* const* d_in, const int* in_sizes, int n_in,
                              void* d_out, int out_size, void* d_ws,
                              size_t ws_size, hipStream_t stream) {
  const int* kpm = (const int*)d_in[1];
  float* outp = (float*)d_out;
  const size_t SZ = (size_t)BB * HH * SS * 64;  // 6,291,456
  const size_t WSZ = (size_t)DD * DD;           // 589,824
  bf16* p = (bf16*)d_ws;
  bf16* cQ = p; p += SZ;        // canonical query; later reused as vT
  bf16* cWt = p; p += 7 * WSZ;  // slots: q,k,v,kg,vg,qg,o
  bf16* cB = p; p += 7 * DD;
  bf16* q = p; p += SZ;   // heads [bh][s][d]
  bf16* k = p; p += SZ;   // heads
  bf16* v = p; p += SZ;   // heads; later reused as vgT
  bf16* kg = p; p += SZ;  // heads
  bf16* vg = p; p += SZ;  // heads
  bf16* qg = p; p += (size_t)BB * HH * GG * 64;
  bf16* attnout = p; p += SZ;
  float* part = (float*)p;  // 384 * 4160 floats
  int* flag = (int*)(part + (size_t)384 * 4160);
  bf16* vT = cQ;   // aliases: cQ dead after the GEMMs
  bf16* vgT = v;   // v dead after tr_vt pass 1
  const float SC = 0.125f;
  dim3 blk(256);

  P7 wsrc{{d_in[2], d_in[4], d_in[6], d_in[10], d_in[12], d_in[8], d_in[14]}};
  P7 bsrc{{d_in[3], d_in[5], d_in[7], d_in[11], d_in[13], d_in[9], d_in[15]}};

  detect_dtype<<<1, blk, 0, stream>>>((const u16*)d_in[0], flag);
  canon_bf16<<<dim3(2048), blk, 0, stream>>>(d_in[0], cQ, (int)SZ, flag);
  transpose_w7<<<dim3(24, 24, 7), blk, 0, stream>>>(wsrc, cWt, flag);
  canon_bias7<<<dim3(7), blk, 0, stream>>>(bsrc, cB, flag);

  gemm5<<<dim3(64, 30), blk, 0, stream>>>(cQ, cWt, cB, q);
  gemm_one<0><<<dim3(1, 6), blk, 0, stream>>>(cQ, cWt + 5 * WSZ, cB + 5 * DD,
                                              qg, GG, SC);
  tr_vt<<<dim3(64, 24), blk, 0, stream>>>(v, vT);
  tr_vt<<<dim3(64, 24), blk, 0, stream>>>(vg, vgT);
  attn_local128<<<dim3(24 * 32), blk, 0, stream>>>(q, k, vT, kpm, attnout);
  attn_glb<<<dim3(BB * HH * 16), blk, 0, stream>>>(qg, kg, vgT, kpm, part);
  attn_comb<<<dim3(BB * HH * 16), blk, 0, stream>>>(part, attnout);
  gemm_one<1><<<dim3(64, 6), blk, 0, stream>>>(attnout, cWt + 6 * WSZ,
                                               cB + 6 * DD, outp, 0, 1.f);
}

// Round 6
// 300.686 us; speedup vs baseline: 6.6488x; 1.0123x over previous
//
#include <hip/hip_runtime.h>
#include <hip/hip_bf16.h>
#include <cstdint>

#define BB 2
#define SS 4096
#define DD 768
#define HH 12
#define GG 64
#define WW 256

typedef __hip_bfloat16 bf16;
typedef unsigned short u16;
typedef __attribute__((ext_vector_type(8))) short short8v;
typedef __attribute__((ext_vector_type(4))) float floatx4;
typedef __attribute__((ext_vector_type(16))) float floatx16;

__device__ __forceinline__ float b2f(u16 u) {
  return __uint_as_float(((unsigned int)u) << 16);
}
__device__ __forceinline__ u16 f2bu(float f) {
  bf16 h = __float2bfloat16(f);
  return *reinterpret_cast<u16*>(&h);
}
__device__ __forceinline__ void async_copy16(const u16* g, u16* l) {
  __builtin_amdgcn_global_load_lds(
      (const __attribute__((address_space(1))) void*)g,
      (__attribute__((address_space(3))) void*)l, 16, 0, 0);
}

struct P7 { const void* p[7]; };

// ---- dtype detect (inputs may be fp32 or bf16) ----
__global__ __launch_bounds__(256) void detect_dtype(const u16* __restrict__ q,
                                                    int* __restrict__ flag) {
  __shared__ int cnt;
  int tid = threadIdx.x;
  if (tid == 0) cnt = 0;
  __syncthreads();
  int bad = 0;
#pragma unroll
  for (int i = 0; i < 16; ++i) {
    float f = b2f(q[tid * 16 + i]);
    if (!isfinite(f) || fabsf(f) > 100.f) bad++;
  }
  atomicAdd(&cnt, bad);
  __syncthreads();
  if (tid == 0) *flag = (cnt > 256) ? 1 : 0;
}

// ---- fused prep: z<7 -> transpose W_z (32x32 tiles); z==7 -> canon query;
//      z==8 -> canon 7 biases.
__global__ __launch_bounds__(256) void prep(P7 wsrc, P7 bsrc,
                                            const void* __restrict__ qsrc,
                                            bf16* __restrict__ cWt,
                                            bf16* __restrict__ cB,
                                            bf16* __restrict__ cQ,
                                            const int* __restrict__ flag) {
  bool f32 = (*flag != 0);
  int z = blockIdx.z;
  if (z < 7) {
    __shared__ float tile[32][33];
    const void* src = wsrc.p[z];
    bf16* d = cWt + (size_t)z * DD * DD;
    int tx = threadIdx.x & 31, ty = threadIdx.x >> 5;
    int k0 = blockIdx.x * 32, n0 = blockIdx.y * 32;
#pragma unroll
    for (int i = 0; i < 32; i += 8) {
      int k = k0 + ty + i, n = n0 + tx;
      float v = f32 ? ((const float*)src)[(size_t)k * DD + n]
                    : b2f(((const u16*)src)[(size_t)k * DD + n]);
      tile[ty + i][tx] = v;
    }
    __syncthreads();
#pragma unroll
    for (int i = 0; i < 32; i += 8) {
      int n = n0 + ty + i, k = k0 + tx;
      d[(size_t)n * DD + k] = __float2bfloat16(tile[tx][ty + i]);
    }
  } else if (z == 7) {
    int bidx = blockIdx.x + 24 * blockIdx.y;  // 576 blocks
    const int n = BB * HH * SS * 64;
    for (int i = bidx * 256 + threadIdx.x; i < n; i += 576 * 256) {
      float v = f32 ? ((const float*)qsrc)[i] : b2f(((const u16*)qsrc)[i]);
      cQ[i] = __float2bfloat16(v);
    }
  } else {
    int which = blockIdx.x;
    if (which >= 7 || blockIdx.y != 0) return;
    const void* s = bsrc.p[which];
    for (int j = threadIdx.x; j < DD; j += 256)
      cB[which * DD + j] =
          __float2bfloat16(f32 ? ((const float*)s)[j] : b2f(((const u16*)s)[j]));
  }
}

// Heads [bh][s][d] -> [bh][d][s] transpose, 64x64 tiles; z picks tensor pair.
__global__ __launch_bounds__(256) void tr_vt2(const bf16* __restrict__ s0,
                                              bf16* __restrict__ d0,
                                              const bf16* __restrict__ s1,
                                              bf16* __restrict__ d1) {
  __shared__ u16 T[64][66];
  int stile = blockIdx.x, bh = blockIdx.y;
  const u16* in = (const u16*)(blockIdx.z ? s1 : s0) + (size_t)bh * SS * 64;
  u16* out = (u16*)(blockIdx.z ? d1 : d0) + (size_t)bh * SS * 64;
  int tid = threadIdx.x;
  int srow = tid >> 2, scol = (tid & 3) * 16;
#pragma unroll
  for (int i = 0; i < 4; ++i) {
    ushort4 u = *(const ushort4*)(in + (size_t)(stile * 64 + srow) * 64 + scol + 4 * i);
    *(ushort2*)&T[srow][scol + 4 * i] = make_ushort2(u.x, u.y);
    *(ushort2*)&T[srow][scol + 4 * i + 2] = make_ushort2(u.z, u.w);
  }
  __syncthreads();
#pragma unroll
  for (int i = 0; i < 4; ++i) {
    ushort4 u;
    u.x = T[scol + 4 * i + 0][srow];
    u.y = T[scol + 4 * i + 1][srow];
    u.z = T[scol + 4 * i + 2][srow];
    u.w = T[scol + 4 * i + 3][srow];
    *(ushort4*)(out + (size_t)srow * SS + stile * 64 + scol + 4 * i) = u;
  }
}

// ---- GEMM core v2: 128x128 tile, BK=64, 32x32x16 MFMA, XOR-swizzled LDS ----
// Logical chunk c (8 u16) of row r stored at chunk c ^ (r&7).
__device__ __forceinline__ void stage_tile(const u16* __restrict__ gp,
                                           size_t row0, u16 (*Ls)[64], int w,
                                           int lane, int k0) {
#pragma unroll
  for (int j = 0; j < 4; ++j)
    async_copy16(gp + (row0 + (size_t)(w * 32 + j * 8 + (lane >> 3))) * DD + k0 +
                     (((lane & 7) ^ ((lane >> 3) & 7)) << 3),
                 &Ls[w * 32 + j * 8][0]);
}
// Fragment: rows base+(lane&31), k = kk + (lane>>5)*8 .. +7
__device__ __forceinline__ short8v lda(u16 (*Ls)[64], int base, int lane, int kk) {
  int row = base + (lane & 31);
  int c = (kk >> 3) + (lane >> 5);
  return *(const short8v*)&Ls[row][((c ^ (row & 7)) << 3)];
}

// acc[nt][mt] = C[n][m] 32x32 frag: A = weight rows (n), B = X rows (m).
__device__ __forceinline__ void gemm_core2(const u16* __restrict__ Xp,
                                           const u16* __restrict__ Wp, int bm,
                                           int bn, int tid, u16 (*As)[64],
                                           u16 (*Bs)[64], floatx16 (&acc)[2][2]) {
  int lane = tid & 63, w = tid >> 6;
  int wm = (w >> 1) * 64, wn = (w & 1) * 64;
  for (int k0 = 0; k0 < DD; k0 += 64) {
    __syncthreads();
    stage_tile(Wp, (size_t)bn, As, w, lane, k0);
    stage_tile(Xp, (size_t)bm, Bs, w, lane, k0);
    __syncthreads();
#pragma unroll
    for (int kk = 0; kk < 64; kk += 16) {
      short8v a0 = lda(As, wn, lane, kk);
      short8v a1 = lda(As, wn + 32, lane, kk);
      short8v b0 = lda(Bs, wm, lane, kk);
      short8v b1 = lda(Bs, wm + 32, lane, kk);
      acc[0][0] = __builtin_amdgcn_mfma_f32_32x32x16_bf16(a0, b0, acc[0][0], 0, 0, 0);
      acc[0][1] = __builtin_amdgcn_mfma_f32_32x32x16_bf16(a0, b1, acc[0][1], 0, 0, 0);
      acc[1][0] = __builtin_amdgcn_mfma_f32_32x32x16_bf16(a1, b0, acc[1][0], 0, 0, 0);
      acc[1][1] = __builtin_amdgcn_mfma_f32_32x32x16_bf16(a1, b1, acc[1][1], 0, 0, 0);
    }
  }
}

// Fused 6 projections. by<30: which=by/6 in {0:q,1:k,2:v,3:kg,4:vg}; by==30:
// which=5 (qg), bx<6 are its n-tiles. Heads layout out.
__global__ __launch_bounds__(256, 4) void gemm5(const bf16* __restrict__ Xb,
                                                const bf16* __restrict__ Wt0,
                                                const bf16* __restrict__ b0,
                                                bf16* __restrict__ out0,
                                                bf16* __restrict__ qg) {
  __shared__ __align__(16) u16 As[128][64];
  __shared__ __align__(16) u16 Bs[128][64];
  int tid = threadIdx.x, lane = tid & 63, w = tid >> 6;
  int wm = (w >> 1) * 64, wn = (w & 1) * 64;
  int which, bn, bm;
  if (blockIdx.y == 30) {
    if (blockIdx.x >= 6) return;
    which = 5;
    bn = blockIdx.x * 128;
    bm = 0;
  } else {
    which = blockIdx.y / 6;
    bn = (blockIdx.y % 6) * 128;
    bm = blockIdx.x * 128;
  }
  const u16* Wp = (const u16*)Wt0 + (size_t)which * DD * DD;
  const u16* bias = (const u16*)b0 + which * DD;
  int Sdim = (which == 5) ? GG : SS;
  u16* outp = (which == 5) ? (u16*)qg
                           : (u16*)out0 + (size_t)which * BB * HH * SS * 64;
  float scale = (which == 0 || which == 5) ? 0.125f : 1.f;
  floatx16 acc[2][2];
#pragma unroll
  for (int i = 0; i < 2; ++i)
#pragma unroll
    for (int j = 0; j < 2; ++j) acc[i][j] = (floatx16)(0.f);
  gemm_core2((const u16*)Xb, Wp, bm, bn, tid, As, Bs, acc);
#pragma unroll
  for (int nt = 0; nt < 2; ++nt) {
    int n0 = bn + wn + nt * 32;
    int h = n0 >> 6;
    int nsub = (n0 & 63) + ((lane >> 5) << 2);
    ushort4 bi[4];
#pragma unroll
    for (int g = 0; g < 4; ++g)
      bi[g] = *(const ushort4*)&bias[n0 + ((lane >> 5) << 2) + g * 8];
#pragma unroll
    for (int mt = 0; mt < 2; ++mt) {
      int m = bm + wm + mt * 32 + (lane & 31);
      int s = m >> 1, b = m & 1;
      u16* outb = outp + ((size_t)(b * HH + h) * Sdim + s) * 64 + nsub;
#pragma unroll
      for (int g = 0; g < 4; ++g) {
        ushort4 o;
        o.x = f2bu((acc[nt][mt][4 * g + 0] + b2f(bi[g].x)) * scale);
        o.y = f2bu((acc[nt][mt][4 * g + 1] + b2f(bi[g].y)) * scale);
        o.z = f2bu((acc[nt][mt][4 * g + 2] + b2f(bi[g].z)) * scale);
        o.w = f2bu((acc[nt][mt][4 * g + 3] + b2f(bi[g].w)) * scale);
        *(ushort4*)(outb + g * 8) = o;
      }
    }
  }
}

// Output projection: fp32 flat out[m*768+n].
__global__ __launch_bounds__(256, 4) void gemm_out(const bf16* __restrict__ Xb,
                                                   const bf16* __restrict__ Wtb,
                                                   const bf16* __restrict__ biasb,
                                                   float* __restrict__ outv) {
  __shared__ __align__(16) u16 As[128][64];
  __shared__ __align__(16) u16 Bs[128][64];
  int tid = threadIdx.x, lane = tid & 63, w = tid >> 6;
  int wm = (w >> 1) * 64, wn = (w & 1) * 64;
  int bm = blockIdx.x * 128, bn = blockIdx.y * 128;
  floatx16 acc[2][2];
#pragma unroll
  for (int i = 0; i < 2; ++i)
#pragma unroll
    for (int j = 0; j < 2; ++j) acc[i][j] = (floatx16)(0.f);
  gemm_core2((const u16*)Xb, (const u16*)Wtb, bm, bn, tid, As, Bs, acc);
  const u16* bias = (const u16*)biasb;
#pragma unroll
  for (int nt = 0; nt < 2; ++nt) {
    int n0 = bn + wn + nt * 32 + ((lane >> 5) << 2);
    ushort4 bi[4];
#pragma unroll
    for (int g = 0; g < 4; ++g) bi[g] = *(const ushort4*)&bias[n0 + g * 8];
#pragma unroll
    for (int mt = 0; mt < 2; ++mt) {
      int m = bm + wm + mt * 32 + (lane & 31);
      float* outb = outv + (size_t)m * DD + n0;
#pragma unroll
      for (int g = 0; g < 4; ++g) {
        float4 o;
        o.x = acc[nt][mt][4 * g + 0] + b2f(bi[g].x);
        o.y = acc[nt][mt][4 * g + 1] + b2f(bi[g].y);
        o.z = acc[nt][mt][4 * g + 2] + b2f(bi[g].z);
        o.w = acc[nt][mt][4 * g + 3] + b2f(bi[g].w);
        *(float4*)(outb + g * 8) = o;
      }
    }
  }
}

// ---- MFMA flash attention, 128-row Q tiles, async staging, swapped PV ----
__global__ __launch_bounds__(256, 3) void attn_local128(
    const bf16* __restrict__ qb, const bf16* __restrict__ kb,
    const bf16* __restrict__ vtb, const int* __restrict__ kpm,
    bf16* __restrict__ attnout) {
  __shared__ __align__(16) u16 Qs[128][64];
  __shared__ __align__(16) u16 Ks[64][64];
  __shared__ __align__(16) u16 Vt[64][64];  // [d][key]
  __shared__ __align__(16) u16 Ps[128][72];  // swizzled
  __shared__ float Ls[128];
  __shared__ int kbadS[64];
  int bid = blockIdx.x;
  int tile = bid & 31, bh = bid >> 5;
  int b = bh / HH, h = bh % HH;
  int tid = threadIdx.x, lane = tid & 63, w = tid >> 6;
  int quad = lane >> 4, t = lane & 15;
  const u16* qp = (const u16*)qb + (size_t)bh * SS * 64;
  const u16* kp = (const u16*)kb + (size_t)bh * SS * 64;
  const u16* vp = (const u16*)vtb + (size_t)bh * SS * 64;  // rows are d
  int sq0 = GG + tile * 128;
#pragma unroll
  for (int j = 0; j < 4; ++j) {
    int qr = sq0 + w * 32 + j * 8 + (lane >> 3);
    int sr = qr < SS ? qr : SS - 1;
    async_copy16(qp + (size_t)sr * 64 + (lane & 7) * 8, &Qs[w * 32 + j * 8][0]);
  }
  __syncthreads();
  short8v aq[2][2];
#pragma unroll
  for (int st = 0; st < 2; ++st)
#pragma unroll
    for (int ks = 0; ks < 2; ++ks)
      aq[st][ks] = *(const short8v*)&Qs[w * 32 + st * 16 + t][ks * 32 + quad * 8];
  floatx4 O[2][4];
#pragma unroll
  for (int st = 0; st < 2; ++st)
#pragma unroll
    for (int dt = 0; dt < 4; ++dt) O[st][dt] = (floatx4)(0.f);
  float ps[2][4] = {};
  int win_lo = max(sq0 - WW, GG);
  int win_hi = min(sq0 + 127 + WW, SS - 1);
  int kb_lo = win_lo & ~63;
  int iters = ((win_hi - kb_lo) >> 6) + 2;  // +1: global-keys block
  for (int it = 0; it < iters; ++it) {
    int kbs = (it == 0) ? 0 : kb_lo + ((it - 1) << 6);
    __syncthreads();
#pragma unroll
    for (int j = 0; j < 2; ++j) {
      async_copy16(kp + (size_t)(kbs + w * 16 + j * 8 + (lane >> 3)) * 64 +
                       (lane & 7) * 8,
                   &Ks[w * 16 + j * 8][0]);
      async_copy16(vp + (size_t)(w * 16 + j * 8 + (lane >> 3)) * SS + kbs +
                       (lane & 7) * 8,
                   &Vt[w * 16 + j * 8][0]);
    }
    if (tid < 64) kbadS[tid] = kpm[b * SS + kbs + tid];
    __syncthreads();
#pragma unroll
    for (int st = 0; st < 2; ++st) {
      floatx4 S[4];
#pragma unroll
      for (int nt = 0; nt < 4; ++nt) {
        S[nt] = (floatx4)(0.f);
#pragma unroll
        for (int ks = 0; ks < 2; ++ks) {
          short8v bk = *(const short8v*)&Ks[nt * 16 + t][ks * 32 + quad * 8];
          S[nt] = __builtin_amdgcn_mfma_f32_16x16x32_bf16(aq[st][ks], bk, S[nt],
                                                          0, 0, 0);
        }
      }
      int prow = w * 32 + st * 16 + quad * 4;
      if (it == 0) {
#pragma unroll
        for (int nt = 0; nt < 4; ++nt)
#pragma unroll
          for (int r = 0; r < 4; ++r) {
            float p = __expf(S[nt][r]);
            ps[st][r] += p;
            Ps[prow + r][((nt ^ quad) << 4) + t] = f2bu(p);
          }
      } else {
#pragma unroll
        for (int r = 0; r < 4; ++r) {
          int qr = sq0 + prow + r;
          int off = kbs + t + WW - qr;
#pragma unroll
          for (int nt = 0; nt < 4; ++nt) {
            int bad = kbadS[nt * 16 + t];
            unsigned u = (unsigned)(off + nt * 16);
            float p = __expf((u <= 2 * WW && bad == 0) ? S[nt][r] : -3.0e38f);
            ps[st][r] += p;
            Ps[prow + r][((nt ^ quad) << 4) + t] = f2bu(p);
          }
        }
      }
    }
    short8v ap[2][2];
#pragma unroll
    for (int st = 0; st < 2; ++st)
#pragma unroll
      for (int ks = 0; ks < 2; ++ks) {
        int chunk = (2 * ks + (quad >> 1)) ^ ((t >> 2) & 3);
        ap[st][ks] = *(const short8v*)&Ps[w * 32 + st * 16 + t]
                                        [(chunk << 4) + ((quad & 1) << 3)];
      }
#pragma unroll
    for (int dt = 0; dt < 4; ++dt) {
#pragma unroll
      for (int ks = 0; ks < 2; ++ks) {
        short8v av = *(const short8v*)&Vt[dt * 16 + t][ks * 32 + quad * 8];
#pragma unroll
        for (int st = 0; st < 2; ++st)
          O[st][dt] = __builtin_amdgcn_mfma_f32_16x16x32_bf16(av, ap[st][ks],
                                                              O[st][dt], 0, 0, 0);
      }
    }
  }
#pragma unroll
  for (int st = 0; st < 2; ++st) {
#pragma unroll
    for (int r = 0; r < 4; ++r)
#pragma unroll
      for (int off = 1; off < 16; off <<= 1) ps[st][r] += __shfl_xor(ps[st][r], off);
    if (t == 0)
#pragma unroll
      for (int r = 0; r < 4; ++r) Ls[w * 32 + st * 16 + quad * 4 + r] = ps[st][r];
  }
#pragma unroll
  for (int st = 0; st < 2; ++st) {
    int q = sq0 + w * 32 + st * 16 + t;
    if (q < SS) {
      float linv = 1.0f / Ls[w * 32 + st * 16 + t];
#pragma unroll
      for (int dt = 0; dt < 4; ++dt) {
        ushort4 o;
        o.x = f2bu(O[st][dt][0] * linv);
        o.y = f2bu(O[st][dt][1] * linv);
        o.z = f2bu(O[st][dt][2] * linv);
        o.w = f2bu(O[st][dt][3] * linv);
        *(ushort4*)((u16*)attnout + ((size_t)q * BB + b) * DD + h * 64 +
                    dt * 16 + quad * 4) = o;
      }
    }
  }
}

// Global-row attention (rows < G), 256-key segment per block; fp32 partials.
__global__ __launch_bounds__(256) void attn_glb(
    const bf16* __restrict__ qgb, const bf16* __restrict__ kgb,
    const bf16* __restrict__ vtb, const int* __restrict__ kpm,
    float* __restrict__ part) {
  __shared__ __align__(16) u16 Qs[64][72];
  __shared__ __align__(16) u16 Ks[64][72];
  __shared__ __align__(16) u16 Vt[64][72];
  __shared__ __align__(16) u16 Ps[64][72];
  __shared__ int kbadS[64];
  int bid = blockIdx.x;
  int bh = bid >> 4, seg = bid & 15;
  int b = bh / HH;
  int tid = threadIdx.x, lane = tid & 63, w = tid >> 6;
  int quad = lane >> 4, t = lane & 15;
  const u16* qp = (const u16*)qgb + (size_t)bh * GG * 64;
  const u16* kp = (const u16*)kgb + (size_t)bh * SS * 64;
  const u16* vp = (const u16*)vtb + (size_t)bh * SS * 64;  // rows are d
  int srow = tid >> 2, scol = (tid & 3) * 16;
#pragma unroll
  for (int i = 0; i < 4; ++i)
    *(ushort4*)&Qs[srow][scol + 4 * i] =
        *(const ushort4*)(qp + (size_t)srow * 64 + scol + 4 * i);
  __syncthreads();
  short8v aq[2];
#pragma unroll
  for (int ks = 0; ks < 2; ++ks)
    aq[ks] = *(const short8v*)&Qs[16 * w + t][ks * 32 + quad * 8];
  floatx4 O[4];
#pragma unroll
  for (int i = 0; i < 4; ++i) O[i] = (floatx4)(0.f);
  float ps[4] = {0.f, 0.f, 0.f, 0.f};
  for (int it = 0; it < 4; ++it) {
    int kbs = (seg << 8) + (it << 6);
    ushort4 ku[4], vu[4];
#pragma unroll
    for (int i = 0; i < 4; ++i) {
      ku[i] = *(const ushort4*)(kp + (size_t)(kbs + srow) * 64 + scol + 4 * i);
      vu[i] = *(const ushort4*)(vp + (size_t)srow * SS + kbs + scol + 4 * i);
    }
    int kbval = (tid < 64) ? kpm[b * SS + kbs + tid] : 0;
    __syncthreads();
#pragma unroll
    for (int i = 0; i < 4; ++i) {
      *(ushort4*)&Ks[srow][scol + 4 * i] = ku[i];
      *(ushort4*)&Vt[srow][scol + 4 * i] = vu[i];
    }
    if (tid < 64) kbadS[tid] = kbval;
    __syncthreads();
    floatx4 S[4];
#pragma unroll
    for (int nt = 0; nt < 4; ++nt) {
      S[nt] = (floatx4)(0.f);
#pragma unroll
      for (int ks = 0; ks < 2; ++ks) {
        short8v bk = *(const short8v*)&Ks[nt * 16 + t][ks * 32 + quad * 8];
        S[nt] = __builtin_amdgcn_mfma_f32_16x16x32_bf16(aq[ks], bk, S[nt], 0, 0, 0);
      }
    }
#pragma unroll
    for (int nt = 0; nt < 4; ++nt) {
      int bad = kbadS[nt * 16 + t];
#pragma unroll
      for (int r = 0; r < 4; ++r) {
        float p = __expf((bad <= 0) ? S[nt][r] : -3.0e38f);
        ps[r] += p;
        Ps[16 * w + quad * 4 + r][((nt ^ quad) << 4) + t] = f2bu(p);
      }
    }
    short8v ap[2];
#pragma unroll
    for (int ks = 0; ks < 2; ++ks) {
      int chunk = (2 * ks + (quad >> 1)) ^ ((t >> 2) & 3);
      ap[ks] = *(const short8v*)&Ps[16 * w + t][(chunk << 4) + ((quad & 1) << 3)];
    }
#pragma unroll
    for (int dt = 0; dt < 4; ++dt)
#pragma unroll
      for (int ks = 0; ks < 2; ++ks) {
        short8v bv = *(const short8v*)&Vt[dt * 16 + t][ks * 32 + quad * 8];
        O[dt] = __builtin_amdgcn_mfma_f32_16x16x32_bf16(ap[ks], bv, O[dt], 0, 0, 0);
      }
  }
#pragma unroll
  for (int r = 0; r < 4; ++r)
#pragma unroll
    for (int off = 1; off < 16; off <<= 1) ps[r] += __shfl_xor(ps[r], off);
  float* pO = part + (size_t)bid * 4160;
#pragma unroll
  for (int dt = 0; dt < 4; ++dt)
#pragma unroll
    for (int r = 0; r < 4; ++r)
      pO[(16 * w + quad * 4 + r) * 64 + dt * 16 + t] = O[dt][r];
  if (t == 0)
#pragma unroll
    for (int r = 0; r < 4; ++r) pO[4096 + 16 * w + quad * 4 + r] = ps[r];
}

__global__ __launch_bounds__(256) void attn_comb(const float* __restrict__ part,
                                                 bf16* __restrict__ attnout) {
  int tid = threadIdx.x, lane = tid & 63, w = tid >> 6;
  int idx = blockIdx.x * 4 + w;  // [0, B*H*64)
  int bh = idx >> 6, row = idx & 63;
  int b = bh / HH, h = bh % HH;
  float o = 0.f, L = 0.f;
#pragma unroll
  for (int s16 = 0; s16 < 16; ++s16) {
    const float* p = part + (size_t)(bh * 16 + s16) * 4160;
    o += p[(row << 6) + lane];
    L += p[4096 + row];
  }
  attnout[((size_t)row * BB + b) * DD + h * 64 + lane] = __float2bfloat16(o / L);
}

extern "C" void kernel_launch(void* const* d_in, const int* in_sizes, int n_in,
                              void* d_out, int out_size, void* d_ws,
                              size_t ws_size, hipStream_t stream) {
  const int* kpm = (const int*)d_in[1];
  float* outp = (float*)d_out;
  const size_t SZ = (size_t)BB * HH * SS * 64;  // 6,291,456
  const size_t WSZ = (size_t)DD * DD;           // 589,824
  bf16* p = (bf16*)d_ws;
  bf16* cQ = p; p += SZ;        // canonical query; later reused as vT
  bf16* cWt = p; p += 7 * WSZ;  // slots: q,k,v,kg,vg,qg,o
  bf16* cB = p; p += 7 * DD;
  bf16* q = p; p += SZ;   // heads [bh][s][d]   (gemm5 which=0..4 outputs
  bf16* k = p; p += SZ;   //  must stay contiguous in this order)
  bf16* v = p; p += SZ;   // heads; later reused as vgT
  bf16* kg = p; p += SZ;  // heads
  bf16* vg = p; p += SZ;  // heads
  bf16* qg = p; p += (size_t)BB * HH * GG * 64;
  bf16* attnout = p; p += SZ;
  float* part = (float*)p;  // 384 * 4160 floats
  int* flag = (int*)(part + (size_t)384 * 4160);
  bf16* vT = cQ;   // aliases: cQ dead after the GEMMs
  bf16* vgT = v;   // v dead after tr_vt2 z=0
  dim3 blk(256);
  (void)kg; (void)vg;

  P7 wsrc{{d_in[2], d_in[4], d_in[6], d_in[10], d_in[12], d_in[8], d_in[14]}};
  P7 bsrc{{d_in[3], d_in[5], d_in[7], d_in[11], d_in[13], d_in[9], d_in[15]}};

  detect_dtype<<<1, blk, 0, stream>>>((const u16*)d_in[0], flag);
  prep<<<dim3(24, 24, 9), blk, 0, stream>>>(wsrc, bsrc, d_in[0], cWt, cB, cQ, flag);
  gemm5<<<dim3(64, 31), blk, 0, stream>>>(cQ, cWt, cB, q, qg);
  tr_vt2<<<dim3(64, 24, 2), blk, 0, stream>>>(v, vT, vg, vgT);
  attn_local128<<<dim3(24 * 32), blk, 0, stream>>>(q, k, vT, kpm, attnout);
  attn_glb<<<dim3(BB * HH * 16), blk, 0, stream>>>(qg, kg, vgT, kpm, part);
  attn_comb<<<dim3(BB * HH * 16), blk, 0, stream>>>(part, attnout);
  gemm_out<<<dim3(64, 6), blk, 0, stream>>>(attnout, cWt + 6 * WSZ, cB + 6 * DD, outp);
}

// Round 7
// 294.193 us; speedup vs baseline: 6.7956x; 1.0221x over previous
//
#include <hip/hip_runtime.h>
#include <hip/hip_bf16.h>
#include <cstdint>

#define BB 2
#define SS 4096
#define DD 768
#define HH 12
#define GG 64
#define WW 256

typedef __hip_bfloat16 bf16;
typedef unsigned short u16;
typedef __attribute__((ext_vector_type(8))) short short8v;
typedef __attribute__((ext_vector_type(4))) float floatx4;
typedef __attribute__((ext_vector_type(16))) float floatx16;

// 0.125 * log2(e): softmax computed with exp2 (v_exp_f32 native)
#define QSCALE 0.18033688011112042f

__device__ __forceinline__ float b2f(u16 u) {
  return __uint_as_float(((unsigned int)u) << 16);
}
__device__ __forceinline__ u16 f2bu(float f) {
  bf16 h = __float2bfloat16(f);
  return *reinterpret_cast<u16*>(&h);
}
__device__ __forceinline__ void async_copy16(const u16* g, u16* l) {
  __builtin_amdgcn_global_load_lds(
      (const __attribute__((address_space(1))) void*)g,
      (__attribute__((address_space(3))) void*)l, 16, 0, 0);
}

struct P7 { const void* p[7]; };

// ---- dtype detect (inputs may be fp32 or bf16) ----
__global__ __launch_bounds__(256) void detect_dtype(const u16* __restrict__ q,
                                                    int* __restrict__ flag) {
  __shared__ int cnt;
  int tid = threadIdx.x;
  if (tid == 0) cnt = 0;
  __syncthreads();
  int bad = 0;
#pragma unroll
  for (int i = 0; i < 16; ++i) {
    float f = b2f(q[tid * 16 + i]);
    if (!isfinite(f) || fabsf(f) > 100.f) bad++;
  }
  atomicAdd(&cnt, bad);
  __syncthreads();
  if (tid == 0) *flag = (cnt > 256) ? 1 : 0;
}

// ---- fused prep: z<7 -> transpose W_z (32x32 tiles); z==7 -> canon query;
//      z==8 -> canon 7 biases.
__global__ __launch_bounds__(256) void prep(P7 wsrc, P7 bsrc,
                                            const void* __restrict__ qsrc,
                                            bf16* __restrict__ cWt,
                                            bf16* __restrict__ cB,
                                            bf16* __restrict__ cQ,
                                            const int* __restrict__ flag) {
  bool f32 = (*flag != 0);
  int z = blockIdx.z;
  if (z < 7) {
    __shared__ float tile[32][33];
    const void* src = wsrc.p[z];
    bf16* d = cWt + (size_t)z * DD * DD;
    int tx = threadIdx.x & 31, ty = threadIdx.x >> 5;
    int k0 = blockIdx.x * 32, n0 = blockIdx.y * 32;
#pragma unroll
    for (int i = 0; i < 32; i += 8) {
      int k = k0 + ty + i, n = n0 + tx;
      float v = f32 ? ((const float*)src)[(size_t)k * DD + n]
                    : b2f(((const u16*)src)[(size_t)k * DD + n]);
      tile[ty + i][tx] = v;
    }
    __syncthreads();
#pragma unroll
    for (int i = 0; i < 32; i += 8) {
      int n = n0 + ty + i, k = k0 + tx;
      d[(size_t)n * DD + k] = __float2bfloat16(tile[tx][ty + i]);
    }
  } else if (z == 7) {
    int bidx = blockIdx.x + 24 * blockIdx.y;  // 576 blocks
    const int n = BB * HH * SS * 64;
    for (int i = bidx * 256 + threadIdx.x; i < n; i += 576 * 256) {
      float v = f32 ? ((const float*)qsrc)[i] : b2f(((const u16*)qsrc)[i]);
      cQ[i] = __float2bfloat16(v);
    }
  } else {
    int which = blockIdx.x;
    if (which >= 7 || blockIdx.y != 0) return;
    const void* s = bsrc.p[which];
    for (int j = threadIdx.x; j < DD; j += 256)
      cB[which * DD + j] =
          __float2bfloat16(f32 ? ((const float*)s)[j] : b2f(((const u16*)s)[j]));
  }
}

// Heads [bh][s][d] -> [bh][d][s] transpose, 64x64 tiles; z picks tensor pair.
__global__ __launch_bounds__(256) void tr_vt2(const bf16* __restrict__ s0,
                                              bf16* __restrict__ d0,
                                              const bf16* __restrict__ s1,
                                              bf16* __restrict__ d1) {
  __shared__ u16 T[64][66];
  int stile = blockIdx.x, bh = blockIdx.y;
  const u16* in = (const u16*)(blockIdx.z ? s1 : s0) + (size_t)bh * SS * 64;
  u16* out = (u16*)(blockIdx.z ? d1 : d0) + (size_t)bh * SS * 64;
  int tid = threadIdx.x;
  int srow = tid >> 2, scol = (tid & 3) * 16;
#pragma unroll
  for (int i = 0; i < 4; ++i) {
    ushort4 u = *(const ushort4*)(in + (size_t)(stile * 64 + srow) * 64 + scol + 4 * i);
    *(ushort2*)&T[srow][scol + 4 * i] = make_ushort2(u.x, u.y);
    *(ushort2*)&T[srow][scol + 4 * i + 2] = make_ushort2(u.z, u.w);
  }
  __syncthreads();
#pragma unroll
  for (int i = 0; i < 4; ++i) {
    ushort4 u;
    u.x = T[scol + 4 * i + 0][srow];
    u.y = T[scol + 4 * i + 1][srow];
    u.z = T[scol + 4 * i + 2][srow];
    u.w = T[scol + 4 * i + 3][srow];
    *(ushort4*)(out + (size_t)srow * SS + stile * 64 + scol + 4 * i) = u;
  }
}

// XOR-swizzled [rows][64] LDS: logical chunk c of row r stored at c ^ (r&7).
// Fragment: rows base+(lane&31), k = kk + (lane>>5)*8 .. +7
__device__ __forceinline__ short8v lda(u16 (*Ls)[64], int base, int lane, int kk) {
  int row = base + (lane & 31);
  int c = (kk >> 3) + (lane >> 5);
  return *(const short8v*)&Ls[row][((c ^ (row & 7)) << 3)];
}

// ---- GEMM core v3: 256x128 tile, BK=64, 32x32x16 MFMA ----
// acc[nf][mf] = C[n][m] 32x32 frag: A = weight rows (n), B = X rows (m).
__device__ __forceinline__ void gemm_core3(const u16* __restrict__ Xp,
                                           const u16* __restrict__ Wp, int bm,
                                           int bn, int tid, u16 (*As)[64],
                                           u16 (*Bs)[64], floatx16 (&acc)[4][2]) {
  int lane = tid & 63, w = tid >> 6;
  int wm = w * 64;
  int r8 = lane >> 3;
  int sw = (((lane & 7) ^ (r8 & 7)) << 3);
  for (int k0 = 0; k0 < DD; k0 += 64) {
    __syncthreads();
#pragma unroll
    for (int j = 0; j < 4; ++j)
      async_copy16(Wp + (size_t)(bn + w * 32 + j * 8 + r8) * DD + k0 + sw,
                   &As[w * 32 + j * 8][0]);
#pragma unroll
    for (int j = 0; j < 8; ++j)
      async_copy16(Xp + (size_t)(bm + w * 64 + j * 8 + r8) * DD + k0 + sw,
                   &Bs[w * 64 + j * 8][0]);
    __syncthreads();
#pragma unroll
    for (int kk = 0; kk < 64; kk += 16) {
      short8v a[4], b[2];
#pragma unroll
      for (int nf = 0; nf < 4; ++nf) a[nf] = lda(As, nf * 32, lane, kk);
#pragma unroll
      for (int mf = 0; mf < 2; ++mf) b[mf] = lda(Bs, wm + mf * 32, lane, kk);
#pragma unroll
      for (int nf = 0; nf < 4; ++nf)
#pragma unroll
        for (int mf = 0; mf < 2; ++mf)
          acc[nf][mf] = __builtin_amdgcn_mfma_f32_32x32x16_bf16(
              a[nf], b[mf], acc[nf][mf], 0, 0, 0);
    }
  }
}

// ---- GEMM core v2 (128x128) for the output projection ----
__device__ __forceinline__ void gemm_core2(const u16* __restrict__ Xp,
                                           const u16* __restrict__ Wp, int bm,
                                           int bn, int tid, u16 (*As)[64],
                                           u16 (*Bs)[64], floatx16 (&acc)[2][2]) {
  int lane = tid & 63, w = tid >> 6;
  int wm = (w >> 1) * 64, wn = (w & 1) * 64;
  int r8 = lane >> 3;
  int sw = (((lane & 7) ^ (r8 & 7)) << 3);
  for (int k0 = 0; k0 < DD; k0 += 64) {
    __syncthreads();
#pragma unroll
    for (int j = 0; j < 4; ++j) {
      async_copy16(Wp + (size_t)(bn + w * 32 + j * 8 + r8) * DD + k0 + sw,
                   &As[w * 32 + j * 8][0]);
      async_copy16(Xp + (size_t)(bm + w * 32 + j * 8 + r8) * DD + k0 + sw,
                   &Bs[w * 32 + j * 8][0]);
    }
    __syncthreads();
#pragma unroll
    for (int kk = 0; kk < 64; kk += 16) {
      short8v a0 = lda(As, wn, lane, kk);
      short8v a1 = lda(As, wn + 32, lane, kk);
      short8v b0 = lda(Bs, wm, lane, kk);
      short8v b1 = lda(Bs, wm + 32, lane, kk);
      acc[0][0] = __builtin_amdgcn_mfma_f32_32x32x16_bf16(a0, b0, acc[0][0], 0, 0, 0);
      acc[0][1] = __builtin_amdgcn_mfma_f32_32x32x16_bf16(a0, b1, acc[0][1], 0, 0, 0);
      acc[1][0] = __builtin_amdgcn_mfma_f32_32x32x16_bf16(a1, b0, acc[1][0], 0, 0, 0);
      acc[1][1] = __builtin_amdgcn_mfma_f32_32x32x16_bf16(a1, b1, acc[1][1], 0, 0, 0);
    }
  }
}

// Fused 6 projections, 256x128 tiles. by<30: which=by/6 in {0:q,1:k,2:v,
// 3:kg,4:vg}, bm=bx*256; by==30: which=5 (qg), bx<6 n-tiles, bm=0 (stores
// guarded to s<GG). Heads layout out.
__global__ __launch_bounds__(256, 2) void gemm5(const bf16* __restrict__ Xb,
                                                const bf16* __restrict__ Wt0,
                                                const bf16* __restrict__ b0,
                                                bf16* __restrict__ out0,
                                                bf16* __restrict__ qg) {
  __shared__ __align__(16) u16 As[128][64];
  __shared__ __align__(16) u16 Bs[256][64];
  int tid = threadIdx.x, lane = tid & 63, w = tid >> 6;
  int which, bn, bm;
  if (blockIdx.y == 30) {
    if (blockIdx.x >= 6) return;
    which = 5;
    bn = blockIdx.x * 128;
    bm = 0;
  } else {
    which = blockIdx.y / 6;
    bn = (blockIdx.y % 6) * 128;
    bm = blockIdx.x * 256;
  }
  const u16* Wp = (const u16*)Wt0 + (size_t)which * DD * DD;
  const u16* bias = (const u16*)b0 + which * DD;
  int Sdim = (which == 5) ? GG : SS;
  u16* outp = (which == 5) ? (u16*)qg
                           : (u16*)out0 + (size_t)which * BB * HH * SS * 64;
  float scale = (which == 0 || which == 5) ? QSCALE : 1.f;
  floatx16 acc[4][2];
#pragma unroll
  for (int i = 0; i < 4; ++i)
#pragma unroll
    for (int j = 0; j < 2; ++j) acc[i][j] = (floatx16)(0.f);
  gemm_core3((const u16*)Xb, Wp, bm, bn, tid, As, Bs, acc);
#pragma unroll
  for (int nf = 0; nf < 4; ++nf) {
#pragma unroll
    for (int g = 0; g < 4; ++g) {
      int nbase = bn + nf * 32 + g * 8 + ((lane >> 5) << 2);
      int h = nbase >> 6, nsub = nbase & 63;
      ushort4 bi = *(const ushort4*)&bias[nbase];
#pragma unroll
      for (int mf = 0; mf < 2; ++mf) {
        int m = bm + w * 64 + mf * 32 + (lane & 31);
        int s = m >> 1, b = m & 1;
        if (which == 5 && s >= GG) continue;
        ushort4 o;
        o.x = f2bu((acc[nf][mf][4 * g + 0] + b2f(bi.x)) * scale);
        o.y = f2bu((acc[nf][mf][4 * g + 1] + b2f(bi.y)) * scale);
        o.z = f2bu((acc[nf][mf][4 * g + 2] + b2f(bi.z)) * scale);
        o.w = f2bu((acc[nf][mf][4 * g + 3] + b2f(bi.w)) * scale);
        *(ushort4*)(outp + ((size_t)(b * HH + h) * Sdim + s) * 64 + nsub) = o;
      }
    }
  }
}

// Output projection: fp32 flat out[m*768+n], 128x128 tiles.
__global__ __launch_bounds__(256, 4) void gemm_out(const bf16* __restrict__ Xb,
                                                   const bf16* __restrict__ Wtb,
                                                   const bf16* __restrict__ biasb,
                                                   float* __restrict__ outv) {
  __shared__ __align__(16) u16 As[128][64];
  __shared__ __align__(16) u16 Bs[128][64];
  int tid = threadIdx.x, lane = tid & 63, w = tid >> 6;
  int wm = (w >> 1) * 64, wn = (w & 1) * 64;
  int bm = blockIdx.x * 128, bn = blockIdx.y * 128;
  floatx16 acc[2][2];
#pragma unroll
  for (int i = 0; i < 2; ++i)
#pragma unroll
    for (int j = 0; j < 2; ++j) acc[i][j] = (floatx16)(0.f);
  gemm_core2((const u16*)Xb, (const u16*)Wtb, bm, bn, tid, As, Bs, acc);
  const u16* bias = (const u16*)biasb;
#pragma unroll
  for (int nt = 0; nt < 2; ++nt) {
    int n0 = bn + wn + nt * 32 + ((lane >> 5) << 2);
    ushort4 bi[4];
#pragma unroll
    for (int g = 0; g < 4; ++g) bi[g] = *(const ushort4*)&bias[n0 + g * 8];
#pragma unroll
    for (int mt = 0; mt < 2; ++mt) {
      int m = bm + wm + mt * 32 + (lane & 31);
      float* outb = outv + (size_t)m * DD + n0;
#pragma unroll
      for (int g = 0; g < 4; ++g) {
        float4 o;
        o.x = acc[nt][mt][4 * g + 0] + b2f(bi[g].x);
        o.y = acc[nt][mt][4 * g + 1] + b2f(bi[g].y);
        o.z = acc[nt][mt][4 * g + 2] + b2f(bi[g].z);
        o.w = acc[nt][mt][4 * g + 3] + b2f(bi[g].w);
        *(float4*)(outb + g * 8) = o;
      }
    }
  }
}

// ---- MFMA flash attention, 128-row Q tiles, async staging, swapped PV ----
// q pre-scaled by 0.125*log2(e): probabilities via exp2f.
__global__ __launch_bounds__(256, 3) void attn_local128(
    const bf16* __restrict__ qb, const bf16* __restrict__ kb,
    const bf16* __restrict__ vtb, const int* __restrict__ kpm,
    bf16* __restrict__ attnout) {
  __shared__ __align__(16) u16 Qs[128][64];
  __shared__ __align__(16) u16 Ks[64][64];
  __shared__ __align__(16) u16 Vt[64][64];  // [d][key]
  __shared__ __align__(16) u16 Ps[128][72];  // swizzled
  __shared__ float Ls[128];
  __shared__ int kbadS[64];
  int bid = blockIdx.x;
  int tile = bid & 31, bh = bid >> 5;
  int b = bh / HH, h = bh % HH;
  int tid = threadIdx.x, lane = tid & 63, w = tid >> 6;
  int quad = lane >> 4, t = lane & 15;
  const u16* qp = (const u16*)qb + (size_t)bh * SS * 64;
  const u16* kp = (const u16*)kb + (size_t)bh * SS * 64;
  const u16* vp = (const u16*)vtb + (size_t)bh * SS * 64;  // rows are d
  int sq0 = GG + tile * 128;
#pragma unroll
  for (int j = 0; j < 4; ++j) {
    int qr = sq0 + w * 32 + j * 8 + (lane >> 3);
    int sr = qr < SS ? qr : SS - 1;
    async_copy16(qp + (size_t)sr * 64 + (lane & 7) * 8, &Qs[w * 32 + j * 8][0]);
  }
  __syncthreads();
  short8v aq[2][2];
#pragma unroll
  for (int st = 0; st < 2; ++st)
#pragma unroll
    for (int ks = 0; ks < 2; ++ks)
      aq[st][ks] = *(const short8v*)&Qs[w * 32 + st * 16 + t][ks * 32 + quad * 8];
  floatx4 O[2][4];
#pragma unroll
  for (int st = 0; st < 2; ++st)
#pragma unroll
    for (int dt = 0; dt < 4; ++dt) O[st][dt] = (floatx4)(0.f);
  float ps[2][4] = {};
  int win_lo = max(sq0 - WW, GG);
  int win_hi = min(sq0 + 127 + WW, SS - 1);
  int kb_lo = win_lo & ~63;
  int iters = ((win_hi - kb_lo) >> 6) + 2;  // +1: global-keys block
  for (int it = 0; it < iters; ++it) {
    int kbs = (it == 0) ? 0 : kb_lo + ((it - 1) << 6);
    __syncthreads();
#pragma unroll
    for (int j = 0; j < 2; ++j) {
      async_copy16(kp + (size_t)(kbs + w * 16 + j * 8 + (lane >> 3)) * 64 +
                       (lane & 7) * 8,
                   &Ks[w * 16 + j * 8][0]);
      async_copy16(vp + (size_t)(w * 16 + j * 8 + (lane >> 3)) * SS + kbs +
                       (lane & 7) * 8,
                   &Vt[w * 16 + j * 8][0]);
    }
    if (tid < 64) kbadS[tid] = kpm[b * SS + kbs + tid];
    __syncthreads();
#pragma unroll
    for (int st = 0; st < 2; ++st) {
      floatx4 S[4];
#pragma unroll
      for (int nt = 0; nt < 4; ++nt) {
        S[nt] = (floatx4)(0.f);
#pragma unroll
        for (int ks = 0; ks < 2; ++ks) {
          short8v bk = *(const short8v*)&Ks[nt * 16 + t][ks * 32 + quad * 8];
          S[nt] = __builtin_amdgcn_mfma_f32_16x16x32_bf16(aq[st][ks], bk, S[nt],
                                                          0, 0, 0);
        }
      }
      int prow = w * 32 + st * 16 + quad * 4;
      if (it == 0) {
#pragma unroll
        for (int nt = 0; nt < 4; ++nt)
#pragma unroll
          for (int r = 0; r < 4; ++r) {
            float p = exp2f(S[nt][r]);
            ps[st][r] += p;
            Ps[prow + r][((nt ^ quad) << 4) + t] = f2bu(p);
          }
      } else {
#pragma unroll
        for (int r = 0; r < 4; ++r) {
          int qr = sq0 + prow + r;
          int off = kbs + t + WW - qr;
#pragma unroll
          for (int nt = 0; nt < 4; ++nt) {
            int bad = kbadS[nt * 16 + t];
            unsigned u = (unsigned)(off + nt * 16);
            float p = exp2f((u <= 2 * WW && bad == 0) ? S[nt][r] : -3.0e38f);
            ps[st][r] += p;
            Ps[prow + r][((nt ^ quad) << 4) + t] = f2bu(p);
          }
        }
      }
    }
    short8v ap[2][2];
#pragma unroll
    for (int st = 0; st < 2; ++st)
#pragma unroll
      for (int ks = 0; ks < 2; ++ks) {
        int chunk = (2 * ks + (quad >> 1)) ^ ((t >> 2) & 3);
        ap[st][ks] = *(const short8v*)&Ps[w * 32 + st * 16 + t]
                                        [(chunk << 4) + ((quad & 1) << 3)];
      }
#pragma unroll
    for (int dt = 0; dt < 4; ++dt) {
#pragma unroll
      for (int ks = 0; ks < 2; ++ks) {
        short8v av = *(const short8v*)&Vt[dt * 16 + t][ks * 32 + quad * 8];
#pragma unroll
        for (int st = 0; st < 2; ++st)
          O[st][dt] = __builtin_amdgcn_mfma_f32_16x16x32_bf16(av, ap[st][ks],
                                                              O[st][dt], 0, 0, 0);
      }
    }
  }
#pragma unroll
  for (int st = 0; st < 2; ++st) {
#pragma unroll
    for (int r = 0; r < 4; ++r)
#pragma unroll
      for (int off = 1; off < 16; off <<= 1) ps[st][r] += __shfl_xor(ps[st][r], off);
    if (t == 0)
#pragma unroll
      for (int r = 0; r < 4; ++r) Ls[w * 32 + st * 16 + quad * 4 + r] = ps[st][r];
  }
#pragma unroll
  for (int st = 0; st < 2; ++st) {
    int q = sq0 + w * 32 + st * 16 + t;
    if (q < SS) {
      float linv = 1.0f / Ls[w * 32 + st * 16 + t];
#pragma unroll
      for (int dt = 0; dt < 4; ++dt) {
        ushort4 o;
        o.x = f2bu(O[st][dt][0] * linv);
        o.y = f2bu(O[st][dt][1] * linv);
        o.z = f2bu(O[st][dt][2] * linv);
        o.w = f2bu(O[st][dt][3] * linv);
        *(ushort4*)((u16*)attnout + ((size_t)q * BB + b) * DD + h * 64 +
                    dt * 16 + quad * 4) = o;
      }
    }
  }
}

// Global-row attention (rows < G), 256-key segment per block; fp32 partials.
__global__ __launch_bounds__(256) void attn_glb(
    const bf16* __restrict__ qgb, const bf16* __restrict__ kgb,
    const bf16* __restrict__ vtb, const int* __restrict__ kpm,
    float* __restrict__ part) {
  __shared__ __align__(16) u16 Qs[64][72];
  __shared__ __align__(16) u16 Ks[64][72];
  __shared__ __align__(16) u16 Vt[64][72];
  __shared__ __align__(16) u16 Ps[64][72];
  __shared__ int kbadS[64];
  int bid = blockIdx.x;
  int bh = bid >> 4, seg = bid & 15;
  int b = bh / HH;
  int tid = threadIdx.x, lane = tid & 63, w = tid >> 6;
  int quad = lane >> 4, t = lane & 15;
  const u16* qp = (const u16*)qgb + (size_t)bh * GG * 64;
  const u16* kp = (const u16*)kgb + (size_t)bh * SS * 64;
  const u16* vp = (const u16*)vtb + (size_t)bh * SS * 64;  // rows are d
  int srow = tid >> 2, scol = (tid & 3) * 16;
#pragma unroll
  for (int i = 0; i < 4; ++i)
    *(ushort4*)&Qs[srow][scol + 4 * i] =
        *(const ushort4*)(qp + (size_t)srow * 64 + scol + 4 * i);
  __syncthreads();
  short8v aq[2];
#pragma unroll
  for (int ks = 0; ks < 2; ++ks)
    aq[ks] = *(const short8v*)&Qs[16 * w + t][ks * 32 + quad * 8];
  floatx4 O[4];
#pragma unroll
  for (int i = 0; i < 4; ++i) O[i] = (floatx4)(0.f);
  float ps[4] = {0.f, 0.f, 0.f, 0.f};
  for (int it = 0; it < 4; ++it) {
    int kbs = (seg << 8) + (it << 6);
    ushort4 ku[4], vu[4];
#pragma unroll
    for (int i = 0; i < 4; ++i) {
      ku[i] = *(const ushort4*)(kp + (size_t)(kbs + srow) * 64 + scol + 4 * i);
      vu[i] = *(const ushort4*)(vp + (size_t)srow * SS + kbs + scol + 4 * i);
    }
    int kbval = (tid < 64) ? kpm[b * SS + kbs + tid] : 0;
    __syncthreads();
#pragma unroll
    for (int i = 0; i < 4; ++i) {
      *(ushort4*)&Ks[srow][scol + 4 * i] = ku[i];
      *(ushort4*)&Vt[srow][scol + 4 * i] = vu[i];
    }
    if (tid < 64) kbadS[tid] = kbval;
    __syncthreads();
    floatx4 S[4];
#pragma unroll
    for (int nt = 0; nt < 4; ++nt) {
      S[nt] = (floatx4)(0.f);
#pragma unroll
      for (int ks = 0; ks < 2; ++ks) {
        short8v bk = *(const short8v*)&Ks[nt * 16 + t][ks * 32 + quad * 8];
        S[nt] = __builtin_amdgcn_mfma_f32_16x16x32_bf16(aq[ks], bk, S[nt], 0, 0, 0);
      }
    }
#pragma unroll
    for (int nt = 0; nt < 4; ++nt) {
      int bad = kbadS[nt * 16 + t];
#pragma unroll
      for (int r = 0; r < 4; ++r) {
        float p = exp2f((bad <= 0) ? S[nt][r] : -3.0e38f);
        ps[r] += p;
        Ps[16 * w + quad * 4 + r][((nt ^ quad) << 4) + t] = f2bu(p);
      }
    }
    short8v ap[2];
#pragma unroll
    for (int ks = 0; ks < 2; ++ks) {
      int chunk = (2 * ks + (quad >> 1)) ^ ((t >> 2) & 3);
      ap[ks] = *(const short8v*)&Ps[16 * w + t][(chunk << 4) + ((quad & 1) << 3)];
    }
#pragma unroll
    for (int dt = 0; dt < 4; ++dt)
#pragma unroll
      for (int ks = 0; ks < 2; ++ks) {
        short8v bv = *(const short8v*)&Vt[dt * 16 + t][ks * 32 + quad * 8];
        O[dt] = __builtin_amdgcn_mfma_f32_16x16x32_bf16(ap[ks], bv, O[dt], 0, 0, 0);
      }
  }
#pragma unroll
  for (int r = 0; r < 4; ++r)
#pragma unroll
    for (int off = 1; off < 16; off <<= 1) ps[r] += __shfl_xor(ps[r], off);
  float* pO = part + (size_t)bid * 4160;
#pragma unroll
  for (int dt = 0; dt < 4; ++dt)
#pragma unroll
    for (int r = 0; r < 4; ++r)
      pO[(16 * w + quad * 4 + r) * 64 + dt * 16 + t] = O[dt][r];
  if (t == 0)
#pragma unroll
    for (int r = 0; r < 4; ++r) pO[4096 + 16 * w + quad * 4 + r] = ps[r];
}

__global__ __launch_bounds__(256) void attn_comb(const float* __restrict__ part,
                                                 bf16* __restrict__ attnout) {
  int tid = threadIdx.x, lane = tid & 63, w = tid >> 6;
  int idx = blockIdx.x * 4 + w;  // [0, B*H*64)
  int bh = idx >> 6, row = idx & 63;
  int b = bh / HH, h = bh % HH;
  float o = 0.f, L = 0.f;
#pragma unroll
  for (int s16 = 0; s16 < 16; ++s16) {
    const float* p = part + (size_t)(bh * 16 + s16) * 4160;
    o += p[(row << 6) + lane];
    L += p[4096 + row];
  }
  attnout[((size_t)row * BB + b) * DD + h * 64 + lane] = __float2bfloat16(o / L);
}

extern "C" void kernel_launch(void* const* d_in, const int* in_sizes, int n_in,
                              void* d_out, int out_size, void* d_ws,
                              size_t ws_size, hipStream_t stream) {
  const int* kpm = (const int*)d_in[1];
  float* outp = (float*)d_out;
  const size_t SZ = (size_t)BB * HH * SS * 64;  // 6,291,456
  const size_t WSZ = (size_t)DD * DD;           // 589,824
  bf16* p = (bf16*)d_ws;
  bf16* cQ = p; p += SZ;        // canonical query; later reused as vT
  bf16* cWt = p; p += 7 * WSZ;  // slots: q,k,v,kg,vg,qg,o
  bf16* cB = p; p += 7 * DD;
  bf16* q = p; p += SZ;   // heads [bh][s][d]   (gemm5 which=0..4 outputs
  bf16* k = p; p += SZ;   //  must stay contiguous in this order)
  bf16* v = p; p += SZ;   // heads; later reused as vgT
  bf16* kg = p; p += SZ;  // heads
  bf16* vg = p; p += SZ;  // heads
  bf16* qg = p; p += (size_t)BB * HH * GG * 64;
  bf16* attnout = p; p += SZ;
  float* part = (float*)p;  // 384 * 4160 floats
  int* flag = (int*)(part + (size_t)384 * 4160);
  bf16* vT = cQ;   // aliases: cQ dead after the GEMMs
  bf16* vgT = v;   // v dead after tr_vt2 z=0
  dim3 blk(256);
  (void)kg; (void)vg;

  P7 wsrc{{d_in[2], d_in[4], d_in[6], d_in[10], d_in[12], d_in[8], d_in[14]}};
  P7 bsrc{{d_in[3], d_in[5], d_in[7], d_in[11], d_in[13], d_in[9], d_in[15]}};

  detect_dtype<<<1, blk, 0, stream>>>((const u16*)d_in[0], flag);
  prep<<<dim3(24, 24, 9), blk, 0, stream>>>(wsrc, bsrc, d_in[0], cWt, cB, cQ, flag);
  gemm5<<<dim3(32, 31), blk, 0, stream>>>(cQ, cWt, cB, q, qg);
  tr_vt2<<<dim3(64, 24, 2), blk, 0, stream>>>(v, vT, vg, vgT);
  attn_local128<<<dim3(24 * 32), blk, 0, stream>>>(q, k, vT, kpm, attnout);
  attn_glb<<<dim3(BB * HH * 16), blk, 0, stream>>>(qg, kg, vgT, kpm, part);
  attn_comb<<<dim3(BB * HH * 16), blk, 0, stream>>>(part, attnout);
  gemm_out<<<dim3(64, 6), blk, 0, stream>>>(attnout, cWt + 6 * WSZ, cB + 6 * DD, outp);
}